// Round 8
// baseline (623.342 us; speedup 1.0000x reference)
//
#include <hip/hip_runtime.h>

#define NPART 1024
#define NNB   512
#define EMAX  2048   // max sub-entries per particle (4*512)

// ---------------------------------------------------------------- prep
__global__ void prep_kernel(const float* __restrict__ p0_enc, const float* __restrict__ v0_enc,
                            const float* __restrict__ p0, const float* __restrict__ v0,
                            const float* __restrict__ a, const float* __restrict__ liftc,
                            const float* __restrict__ liftd,
                            float* __restrict__ featsC, float* __restrict__ Fbuf,
                            float* __restrict__ p1out)
{
    int p = blockIdx.x;          // b*N + i
    int t = threadIdx.x;         // 128 threads: c*8 + m
    int c = t >> 3, m = t & 7;
    float v0x = v0[p*2+0], v0y = v0[p*2+1];
    float ax  = a[p*2+0],  ay  = a[p*2+1];
    float p0x = p0[p*2+0], p0y = p0[p*2+1];
    float v1x = v0x + ax, v1y = v0y + ay;
    float p1x = p0x + 0.5f*(v0x + v1x), p1y = p0y + 0.5f*(v0y + v1y);
    float vx, vy;
    if (c == 0)      { vx = v1x; vy = v1y; }
    else if (c == 1) { vx = p1x; vy = p1y; }
    else if (c < 9)  { vx = v0_enc[(p*7 + (c-2))*2+0]; vy = v0_enc[(p*7 + (c-2))*2+1]; }
    else             { vx = p0_enc[(p*7 + (c-9))*2+0]; vy = p0_enc[(p*7 + (c-9))*2+1]; }
    float th = (float)m * 0.7853981633974483f;
    float cs = cosf(th), sn = sinf(th);
    float lc0 = liftc[0], lc1 = liftc[1];
    float ld0 = liftd[0], ld1 = liftd[1];
    featsC[p*128 + t]        = vx*(lc0*cs - lc1*sn) + vy*(lc0*sn + lc1*cs);
    Fbuf[p*6272 + 6144 + t]  = vx*(ld0*cs - ld1*sn) + vy*(ld0*sn + ld1*cs);  // layer-0 dense tail
    if (t == 0) { p1out[p*2+0] = p1x; p1out[p*2+1] = p1y; }
}

// ---------------------------------------------------------------- pair weights -> per-bin bucketed lists
__global__ void pairs_kernel(const float* __restrict__ p1, const float* __restrict__ mask,
                             float* __restrict__ Ew, unsigned short* __restrict__ Ej,
                             int* __restrict__ offG)
{
    int p  = blockIdx.x;          // b*N + i
    int b  = p >> 9;
    int ii = p & 511;
    int tid = threadIdx.x;        // 256
    __shared__ float red[256];
    __shared__ float denomS;
    __shared__ int bincnt[48];
    __shared__ int binoff[49];
    __shared__ int binpos[48];
    if (tid < 48) bincnt[tid] = 0;
    float pix = p1[p*2+0], piy = p1[p*2+1];
    float relx[2], rely[2], dd[2], ww[2];
#pragma unroll
    for (int q = 0; q < 2; ++q) {
        int j  = tid + q*256;
        int jr = b*NNB + j;
        float rx = p1[jr*2+0] - pix;
        float ry = p1[jr*2+1] - piy;
        float d  = sqrtf(rx*rx + ry*ry + 1e-12f) * (1.0f/40.0f);
        float t1 = fmaxf(1.0f - d*d, 0.0f);
        float w  = t1*t1*t1 * mask[jr];
        relx[q] = rx; rely[q] = ry; dd[q] = d; ww[q] = w;
    }
    red[tid] = ww[0] + ww[1];
    __syncthreads();
    for (int s = 128; s > 0; s >>= 1) {
        if (tid < s) red[tid] += red[tid+s];
        __syncthreads();
    }
    if (tid == 0) denomS = 1.0f / (red[0] + 1e-6f);
    __syncthreads();
    float dinv = denomS;

    float wsub[2][4];
    int   bsub[2][4];
#pragma unroll
    for (int q = 0; q < 2; ++q) {
        int j  = tid + q*256;
        if (ww[q] == 0.0f) {
#pragma unroll
            for (int k = 0; k < 4; ++k) wsub[q][k] = 0.0f;
            continue;
        }
        float wb = ww[q] * dinv;
        float d  = dd[q];
        float rc  = fminf(fmaxf(d*3.0f - 0.5f, 0.0f), 2.0f);
        float r0f = floorf(rc);
        float wr  = rc - r0f;
        int r0 = (int)r0f;
        int r1 = min(r0 + 1, 2);
        float rx = (j == ii) ? 1.0f : relx[q];
        float ry = (j == ii) ? 0.0f : rely[q];
        float ang = atan2f(ry, rx);
        if (ang < 0.0f) ang += 6.283185307179586f;
        float tc  = ang * 2.546479089470325f;   // *16/(2*pi)
        float t0f = floorf(tc);
        float wt  = tc - t0f;
        int t0  = ((int)t0f) & 15;              // tc==16 edge -> bin 0 like ref's %16
        int t1i = (t0 + 1) & 15;
        wsub[q][0] = wb * (1.0f-wr) * (1.0f-wt);  bsub[q][0] = r0*16 + t0;
        wsub[q][1] = wb * (1.0f-wr) * wt;         bsub[q][1] = r0*16 + t1i;
        wsub[q][2] = wb * wr * (1.0f-wt);         bsub[q][2] = r1*16 + t0;
        wsub[q][3] = wb * wr * wt;                bsub[q][3] = r1*16 + t1i;
#pragma unroll
        for (int k = 0; k < 4; ++k)
            if (wsub[q][k] != 0.0f) atomicAdd(&bincnt[bsub[q][k]], 1);
    }
    __syncthreads();
    if (tid == 0) {
        int s = 0;
#pragma unroll
        for (int g = 0; g < 48; ++g) { binoff[g] = s; s += bincnt[g]; }
        binoff[48] = s;
    }
    __syncthreads();
    if (tid < 48) binpos[tid] = binoff[tid];
    if (tid < 49) offG[p*64 + tid] = binoff[tid];
    __syncthreads();
#pragma unroll
    for (int q = 0; q < 2; ++q) {
        int j = tid + q*256;
#pragma unroll
        for (int k = 0; k < 4; ++k) {
            if (wsub[q][k] != 0.0f) {
                int slot = atomicAdd(&binpos[bsub[q][k]], 1);
                Ew[p*EMAX + slot] = wsub[q][k];
                Ej[p*EMAX + slot] = (unsigned short)j;
            }
        }
    }
}

// ---------------------------------------------------------------- aggregation: 6 interleaved bin-streams / wave
// Block = particle, 8 waves; wave wv owns bins g = wv + 8s, s=0..5 (2 bins from each r-ring).
// All 6 streams processed round-robin with 2-deep prefetch each: 12 outstanding loads/wave.
// Slot arrays only indexed inside #pragma unroll loops (static indices, no scratch).
template<int C8>
__global__ __launch_bounds__(512) void aggregate_kernel(const float* __restrict__ actsrc, int actStride,
                                                        const float* __restrict__ Ew,
                                                        const unsigned short* __restrict__ Ej,
                                                        const int* __restrict__ offG,
                                                        float* __restrict__ Fbuf, int Krow)
{
    int p = blockIdx.x;
    int pbase = p & ~511;            // b*N
    int tid  = threadIdx.x;
    int lane = tid & 63;
    int wv   = tid >> 6;             // 0..7
    const float* ew = Ew + p*EMAX;
    const unsigned short* ej = Ej + p*EMAX;
    const int* off = offG + p*64;
    float* dst = Fbuf + (size_t)p * Krow;

    int ec[6], ei[6], e1[6];
    int maxlen = 0;
#pragma unroll
    for (int s = 0; s < 6; ++s) {
        int g = wv + s*8;
        ec[s] = off[g]; ei[s] = ec[s]; e1[s] = off[g+1];
        maxlen = max(maxlen, e1[s] - ec[s]);
    }

    if (C8 == 128) {
        float2 acc[6], fA[6], fB[6];
        float  wA[6], wB[6];
#pragma unroll
        for (int s = 0; s < 6; ++s) {
            acc[s] = {0,0}; fA[s] = {0,0}; fB[s] = {0,0}; wA[s] = 0; wB[s] = 0;
            if (ei[s] < e1[s]) { wA[s] = ew[ei[s]]; fA[s] = ((const float2*)(actsrc + (size_t)(pbase + ej[ei[s]])*actStride))[lane]; ei[s]++; }
        }
#pragma unroll
        for (int s = 0; s < 6; ++s) {
            if (ei[s] < e1[s]) { wB[s] = ew[ei[s]]; fB[s] = ((const float2*)(actsrc + (size_t)(pbase + ej[ei[s]])*actStride))[lane]; ei[s]++; }
        }
        for (int it = 0; it < maxlen; ++it) {
#pragma unroll
            for (int s = 0; s < 6; ++s) {
                if (ec[s] < e1[s]) {
                    float2 f = fA[s]; float w = wA[s];
                    fA[s] = fB[s]; wA[s] = wB[s];
                    if (ei[s] < e1[s]) { wB[s] = ew[ei[s]]; fB[s] = ((const float2*)(actsrc + (size_t)(pbase + ej[ei[s]])*actStride))[lane]; ei[s]++; }
                    acc[s].x += w*f.x; acc[s].y += w*f.y;
                    ec[s]++;
                }
            }
        }
#pragma unroll
        for (int s = 0; s < 6; ++s)
            ((float2*)(dst + (wv + s*8)*C8))[lane] = acc[s];
    } else {
        float acc[6], fA[6], fB[6], wA[6], wB[6];
#pragma unroll
        for (int s = 0; s < 6; ++s) {
            acc[s] = 0; fA[s] = 0; fB[s] = 0; wA[s] = 0; wB[s] = 0;
            if (ei[s] < e1[s]) { wA[s] = ew[ei[s]]; fA[s] = (actsrc + (size_t)(pbase + ej[ei[s]])*actStride)[lane]; ei[s]++; }
        }
#pragma unroll
        for (int s = 0; s < 6; ++s) {
            if (ei[s] < e1[s]) { wB[s] = ew[ei[s]]; fB[s] = (actsrc + (size_t)(pbase + ej[ei[s]])*actStride)[lane]; ei[s]++; }
        }
        for (int it = 0; it < maxlen; ++it) {
#pragma unroll
            for (int s = 0; s < 6; ++s) {
                if (ec[s] < e1[s]) {
                    float f = fA[s]; float w = wA[s];
                    fA[s] = fB[s]; wA[s] = wB[s];
                    if (ei[s] < e1[s]) { wB[s] = ew[ei[s]]; fB[s] = (actsrc + (size_t)(pbase + ej[ei[s]])*actStride)[lane]; ei[s]++; }
                    acc[s] += w*f;
                    ec[s]++;
                }
            }
        }
#pragma unroll
        for (int s = 0; s < 6; ++s)
            dst[(wv + s*8)*C8 + lane] = acc[s];
    }
}

// ---------------------------------------------------------------- expand weights into B matrices
__global__ void expand_kernel(const float* __restrict__ Wc, const float* __restrict__ Wd,
                              const float* __restrict__ pc4, const float* __restrict__ pd4,
                              float* __restrict__ Bm, int C, int O8, int total, int mode)
{
    int e = blockIdx.x*blockDim.x + threadIdx.x;
    if (e >= total) return;
    int col = e % O8;
    int k   = e / O8;
    int C8  = C*8;
    bool conv = (k < 48*C8);
    int cc, nn, rr = 0, tt = 0;
    if (conv) {
        int g = k / C8, rem = k - g*C8;
        cc = rem >> 3; nn = rem & 7; rr = g >> 4; tt = g & 15;
    } else {
        int rem = k - 48*C8;
        cc = rem >> 3; nn = rem & 7;
    }
    float val = 0.0f;
    if (mode == 0) {
        int o = col >> 3, m = col & 7;
        if (conv) val = Wc[(((o*C + cc)*8 + ((nn - m) & 7))*3 + rr)*16 + ((tt - 2*m) & 15)];
        else      val = Wd[(o*C + cc)*8 + ((m - nn) & 7)];
    } else if (mode == 1) {
        int o = col >> 3, m = col & 7;
        if (col < 32) { if (conv)  val = Wc[(((o*C + cc)*8 + ((nn - m)&7))*3 + rr)*16 + ((tt - 2*m)&15)]; }
        else          { if (!conv) val = Wd[((o-4)*C + cc)*8 + ((m - nn)&7)]; }
    } else {
        if (col < 6) {
            int co = col >> 1, aa = col & 1;
            float s0 = conv ? pc4[0] : pd4[0];
            float s1 = conv ? pc4[1] : pd4[1];
#pragma unroll
            for (int m = 0; m < 8; ++m) {
                float th = (float)m * 0.7853981633974483f;
                float csv = cosf(th), snv = sinf(th);
                float bas = (aa == 0) ? (s0*csv - s1*snv) : (s0*snv + s1*csv);
                float wv;
                if (conv) wv = Wc[(((co*C + cc)*8 + ((nn - m)&7))*3 + rr)*16 + ((tt - 2*m)&15)];
                else      wv = Wd[(co*C + cc)*8 + ((m - nn)&7)];
                val += wv * bas;
            }
        }
    }
    Bm[e] = val;
}

// ---------------------------------------------------------------- split-K register-tiled f32 GEMM
template<int N>
__global__ __launch_bounds__(256) void gemm_tile(const float* __restrict__ A, int Kdim,
                                                 const float* __restrict__ B,
                                                 float* __restrict__ Cpart)
{
    constexpr int CT = N/16;               // 1, 4, 8
    __shared__ float As[32][68];           // k-major [kk][row], padded
    __shared__ float Bs[32][N];
    int tid = threadIdx.x;
    int tr = tid & 15, tc = tid >> 4;
    int m0 = blockIdx.x * 64;
    int k0base = blockIdx.y * 224;
    float acc[4][CT];
#pragma unroll
    for (int i = 0; i < 4; ++i)
#pragma unroll
        for (int u = 0; u < CT; ++u) acc[i][u] = 0.0f;

    int ar = tid >> 2, aq = (tid & 3) * 8;
    for (int k0 = 0; k0 < 224; k0 += 32) {
        const float* Ap = A + (size_t)(m0 + ar)*Kdim + k0base + k0 + aq;
        float4 av0 = *(const float4*)(Ap);
        float4 av1 = *(const float4*)(Ap + 4);
        As[aq+0][ar] = av0.x; As[aq+1][ar] = av0.y; As[aq+2][ar] = av0.z; As[aq+3][ar] = av0.w;
        As[aq+4][ar] = av1.x; As[aq+5][ar] = av1.y; As[aq+6][ar] = av1.z; As[aq+7][ar] = av1.w;
#pragma unroll
        for (int u = 0; u < (8*N + 255)/256; ++u) {
            int idx = tid + 256*u;
            if (idx < 8*N) {
                int row = idx / (N/4), c4 = idx % (N/4);
                *(float4*)&Bs[row][c4*4] = *(const float4*)(B + (size_t)(k0base + k0 + row)*N + c4*4);
            }
        }
        __syncthreads();
#pragma unroll
        for (int kk = 0; kk < 32; ++kk) {
            float4 a4 = *(const float4*)&As[kk][tr*4];
            if (CT == 1) {
                float bv = Bs[kk][tc];
                acc[0][0] += a4.x*bv; acc[1][0] += a4.y*bv;
                acc[2][0] += a4.z*bv; acc[3][0] += a4.w*bv;
            } else {
#pragma unroll
                for (int uu = 0; uu < CT; uu += 4) {
                    float4 b4 = *(const float4*)&Bs[kk][tc*CT + uu];
                    acc[0][uu+0] += a4.x*b4.x; acc[0][uu+1] += a4.x*b4.y; acc[0][uu+2] += a4.x*b4.z; acc[0][uu+3] += a4.x*b4.w;
                    acc[1][uu+0] += a4.y*b4.x; acc[1][uu+1] += a4.y*b4.y; acc[1][uu+2] += a4.y*b4.z; acc[1][uu+3] += a4.y*b4.w;
                    acc[2][uu+0] += a4.z*b4.x; acc[2][uu+1] += a4.z*b4.y; acc[2][uu+2] += a4.z*b4.z; acc[2][uu+3] += a4.z*b4.w;
                    acc[3][uu+0] += a4.w*b4.x; acc[3][uu+1] += a4.w*b4.y; acc[3][uu+2] += a4.w*b4.z; acc[3][uu+3] += a4.w*b4.w;
                }
            }
        }
        __syncthreads();
    }
    float* Cp = Cpart + ((size_t)blockIdx.y*1024 + m0)*N;
#pragma unroll
    for (int i = 0; i < 4; ++i)
#pragma unroll
        for (int u = 0; u < CT; ++u)
            Cp[(size_t)(tr*4 + i)*N + tc*CT + u] = acc[i][u];
}

// ---------------------------------------------------------------- epilogue: split-reduce + residual + mag_act
__global__ void epilogue_kernel(const float* __restrict__ Cpart, int S, int O, int res,
                                float* __restrict__ outBuf, float* __restrict__ actDst, int actStride)
{
    int id = blockIdx.x*blockDim.x + threadIdx.x;
    if (id >= NPART*O) return;
    int p = id / O, c = id % O;
    int O8 = O*8;
    float x[8];
#pragma unroll
    for (int m = 0; m < 8; ++m) x[m] = 0.0f;
    for (int s = 0; s < S; ++s) {
        const float4* q = (const float4*)(Cpart + ((size_t)(s*1024 + p))*O8 + c*8);
        float4 u0 = q[0], u1 = q[1];
        x[0]+=u0.x; x[1]+=u0.y; x[2]+=u0.z; x[3]+=u0.w;
        x[4]+=u1.x; x[5]+=u1.y; x[6]+=u1.z; x[7]+=u1.w;
    }
    float* ob = outBuf + (size_t)p*O8 + c*8;
    float mag = 1e-6f;
#pragma unroll
    for (int m = 0; m < 8; ++m) {
        float v = x[m];
        if (res) v += ob[m];
        x[m] = v; mag += v*v;
    }
#pragma unroll
    for (int m = 0; m < 8; ++m) ob[m] = x[m];
    float sc = fmaxf(mag - 0.2f, 0.0f) / mag;
    float* ad = actDst + (size_t)p*actStride + c*8;
#pragma unroll
    for (int m = 0; m < 8; ++m) ad[m] = x[m]*sc;
}

// ---------------------------------------------------------------- final outputs (S splits, N=16 partials)
__global__ void final_kernel(const float* __restrict__ Cpart, int S, const float* __restrict__ p1,
                             const float* __restrict__ p0, float* __restrict__ out)
{
    int p = blockIdx.x*blockDim.x + threadIdx.x;
    if (p >= NPART) return;
    float c[6];
#pragma unroll
    for (int t = 0; t < 6; ++t) c[t] = 0.0f;
    for (int s = 0; s < S; ++s) {
        const float* q = Cpart + ((size_t)(s*1024 + p))*16;
#pragma unroll
        for (int t = 0; t < 6; ++t) c[t] += q[t];
    }
    const float sc = 0.0078125f;  // 1/128
#pragma unroll
    for (int t = 0; t < 6; ++t) c[t] *= sc;
    float pcx = p1[p*2+0] + c[0], pcy = p1[p*2+1] + c[1];
    out[p*2+0] = pcx; out[p*2+1] = pcy;
    out[2048 + p*2+0] = pcx - p0[p*2+0];
    out[2048 + p*2+1] = pcy - p0[p*2+1];
    out[4096 + p*4+0] = c[2]; out[4096 + p*4+1] = c[3];
    out[4096 + p*4+2] = c[4]; out[4096 + p*4+3] = c[5];
}

// ---------------------------------------------------------------- launch
extern "C" void kernel_launch(void* const* d_in, const int* in_sizes, int n_in,
                              void* d_out, int out_size, void* d_ws, size_t ws_size,
                              hipStream_t stream)
{
    const float* p0_enc  = (const float*)d_in[0];
    const float* v0_enc  = (const float*)d_in[1];
    const float* p0      = (const float*)d_in[2];
    const float* v0      = (const float*)d_in[3];
    const float* a       = (const float*)d_in[4];
    const float* mask    = (const float*)d_in[5];
    const float* lift_c0 = (const float*)d_in[6];
    const float* Wc0     = (const float*)d_in[7];
    const float* lift_d0 = (const float*)d_in[8];
    const float* Wd0     = (const float*)d_in[9];
    const float* Wc1     = (const float*)d_in[10];
    const float* Wd1     = (const float*)d_in[11];
    const float* Wc2     = (const float*)d_in[12];
    const float* Wd2     = (const float*)d_in[13];
    const float* Wc3     = (const float*)d_in[14];
    const float* Wd3     = (const float*)d_in[15];
    const float* Wc4     = (const float*)d_in[16];
    const float* pc4     = (const float*)d_in[17];
    const float* Wd4     = (const float*)d_in[18];
    const float* pd4     = (const float*)d_in[19];
    float* out = (float*)d_out;

    float* wsf    = (float*)d_ws;
    float* featsC = wsf;                               // 131072
    float* p1     = featsC + 131072;                   // 2048
    float* Ew     = p1 + 2048;                         // 1024*2048 = 2097152
    unsigned short* Ej = (unsigned short*)(Ew + 2097152);  // 2097152 ushort = 1048576 floats
    int*   offG   = (int*)(Ew + 2097152 + 1048576);    // 1024*64 = 65536
    float* Fbuf   = (float*)offG + 65536;              // 6422528
    float* Cpart  = Fbuf + 1024*6272;                  // 1835008 (28*1024*64 = 14*1024*128)
    float* outBuf = Cpart + 1835008;                   // 131072
    float* Bm0    = outBuf + 131072;                   // 6272*64
    float* Bm1    = Bm0 + 6272*64;                     // 3136*64
    float* Bm2    = Bm1 + 3136*64;                     // 3136*128
    float* Bm3    = Bm2 + 3136*128;                    // 6272*64
    float* Bm4    = Bm3 + 6272*64;                     // 3136*16

    prep_kernel<<<NPART, 128, 0, stream>>>(p0_enc, v0_enc, p0, v0, a, lift_c0, lift_d0,
                                           featsC, Fbuf, p1);
    pairs_kernel<<<NPART, 256, 0, stream>>>(p1, mask, Ew, Ej, offG);

    {   // expand B matrices
        int t0 = 6272*64;  expand_kernel<<<(t0+255)/256, 256, 0, stream>>>(Wc0, Wd0, pc4, pd4, Bm0, 16,  64, t0, 1);
        int t1 = 3136*64;  expand_kernel<<<(t1+255)/256, 256, 0, stream>>>(Wc1, Wd1, pc4, pd4, Bm1,  8,  64, t1, 0);
        int t2 = 3136*128; expand_kernel<<<(t2+255)/256, 256, 0, stream>>>(Wc2, Wd2, pc4, pd4, Bm2,  8, 128, t2, 0);
        int t3 = 6272*64;  expand_kernel<<<(t3+255)/256, 256, 0, stream>>>(Wc3, Wd3, pc4, pd4, Bm3, 16,  64, t3, 0);
        int t4 = 3136*16;  expand_kernel<<<(t4+255)/256, 256, 0, stream>>>(Wc4, Wd4, pc4, pd4, Bm4,  8,  16, t4, 2);
    }

    // Layer 0  (C8=128, K=6272, S=28)
    aggregate_kernel<128><<<NPART, 512, 0, stream>>>(featsC, 128, Ew, Ej, offG, Fbuf, 6272);
    gemm_tile<64><<<dim3(16,28), 256, 0, stream>>>(Fbuf, 6272, Bm0, Cpart);
    epilogue_kernel<<<(NPART*8+63)/64, 64, 0, stream>>>(Cpart, 28, 8, 0, outBuf, Fbuf + 3072, 3136);
    // Layer 1  (C8=64, K=3136, S=14, residual)
    aggregate_kernel<64><<<NPART, 512, 0, stream>>>(Fbuf + 3072, 3136, Ew, Ej, offG, Fbuf, 3136);
    gemm_tile<64><<<dim3(16,14), 256, 0, stream>>>(Fbuf, 3136, Bm1, Cpart);
    epilogue_kernel<<<(NPART*8+63)/64, 64, 0, stream>>>(Cpart, 14, 8, 1, outBuf, Fbuf + 3072, 3136);
    // Layer 2  (C8=64 -> O=16, S=14)
    aggregate_kernel<64><<<NPART, 512, 0, stream>>>(Fbuf + 3072, 3136, Ew, Ej, offG, Fbuf, 3136);
    gemm_tile<128><<<dim3(16,14), 256, 0, stream>>>(Fbuf, 3136, Bm2, Cpart);
    epilogue_kernel<<<(NPART*16+63)/64, 64, 0, stream>>>(Cpart, 14, 16, 0, outBuf, Fbuf + 6144, 6272);
    // Layer 3  (C8=128 -> O=8, S=28)
    aggregate_kernel<128><<<NPART, 512, 0, stream>>>(Fbuf + 6144, 6272, Ew, Ej, offG, Fbuf, 6272);
    gemm_tile<64><<<dim3(16,28), 256, 0, stream>>>(Fbuf, 6272, Bm3, Cpart);
    epilogue_kernel<<<(NPART*8+63)/64, 64, 0, stream>>>(Cpart, 28, 8, 0, outBuf, Fbuf + 3072, 3136);
    // Layer 4  (C8=64 -> N=16 padded, proj folded, S=14)
    aggregate_kernel<64><<<NPART, 512, 0, stream>>>(Fbuf + 3072, 3136, Ew, Ej, offG, Fbuf, 3136);
    gemm_tile<16><<<dim3(16,14), 256, 0, stream>>>(Fbuf, 3136, Bm4, Cpart);
    final_kernel<<<4, 256, 0, stream>>>(Cpart, 14, p1, p0, out);
}

// Round 9
// 527.516 us; speedup vs baseline: 1.1817x; 1.1817x over previous
//
#include <hip/hip_runtime.h>

#define NPART 1024
#define NNB   512
#define EMAX  2048   // max sub-entries per particle (4*512)

// ---------------------------------------------------------------- prep
__global__ void prep_kernel(const float* __restrict__ p0_enc, const float* __restrict__ v0_enc,
                            const float* __restrict__ p0, const float* __restrict__ v0,
                            const float* __restrict__ a, const float* __restrict__ liftc,
                            const float* __restrict__ liftd,
                            float* __restrict__ featsC, float* __restrict__ Fbuf,
                            float* __restrict__ p1out)
{
    int p = blockIdx.x;          // b*N + i
    int t = threadIdx.x;         // 128 threads: c*8 + m
    int c = t >> 3, m = t & 7;
    float v0x = v0[p*2+0], v0y = v0[p*2+1];
    float ax  = a[p*2+0],  ay  = a[p*2+1];
    float p0x = p0[p*2+0], p0y = p0[p*2+1];
    float v1x = v0x + ax, v1y = v0y + ay;
    float p1x = p0x + 0.5f*(v0x + v1x), p1y = p0y + 0.5f*(v0y + v1y);
    float vx, vy;
    if (c == 0)      { vx = v1x; vy = v1y; }
    else if (c == 1) { vx = p1x; vy = p1y; }
    else if (c < 9)  { vx = v0_enc[(p*7 + (c-2))*2+0]; vy = v0_enc[(p*7 + (c-2))*2+1]; }
    else             { vx = p0_enc[(p*7 + (c-9))*2+0]; vy = p0_enc[(p*7 + (c-9))*2+1]; }
    float th = (float)m * 0.7853981633974483f;
    float cs = cosf(th), sn = sinf(th);
    float lc0 = liftc[0], lc1 = liftc[1];
    float ld0 = liftd[0], ld1 = liftd[1];
    featsC[p*128 + t]        = vx*(lc0*cs - lc1*sn) + vy*(lc0*sn + lc1*cs);
    Fbuf[p*6272 + 6144 + t]  = vx*(ld0*cs - ld1*sn) + vy*(ld0*sn + ld1*cs);  // layer-0 dense tail
    if (t == 0) { p1out[p*2+0] = p1x; p1out[p*2+1] = p1y; }
}

// ---------------------------------------------------------------- pair weights -> per-bin bucketed lists
__global__ void pairs_kernel(const float* __restrict__ p1, const float* __restrict__ mask,
                             float* __restrict__ Ew, unsigned short* __restrict__ Ej,
                             int* __restrict__ offG)
{
    int p  = blockIdx.x;          // b*N + i
    int b  = p >> 9;
    int ii = p & 511;
    int tid = threadIdx.x;        // 256
    __shared__ float red[256];
    __shared__ float denomS;
    __shared__ int bincnt[48];
    __shared__ int binoff[49];
    __shared__ int binpos[48];
    if (tid < 48) bincnt[tid] = 0;
    float pix = p1[p*2+0], piy = p1[p*2+1];
    float relx[2], rely[2], dd[2], ww[2];
#pragma unroll
    for (int q = 0; q < 2; ++q) {
        int j  = tid + q*256;
        int jr = b*NNB + j;
        float rx = p1[jr*2+0] - pix;
        float ry = p1[jr*2+1] - piy;
        float d  = sqrtf(rx*rx + ry*ry + 1e-12f) * (1.0f/40.0f);
        float t1 = fmaxf(1.0f - d*d, 0.0f);
        float w  = t1*t1*t1 * mask[jr];
        relx[q] = rx; rely[q] = ry; dd[q] = d; ww[q] = w;
    }
    red[tid] = ww[0] + ww[1];
    __syncthreads();
    for (int s = 128; s > 0; s >>= 1) {
        if (tid < s) red[tid] += red[tid+s];
        __syncthreads();
    }
    if (tid == 0) denomS = 1.0f / (red[0] + 1e-6f);
    __syncthreads();
    float dinv = denomS;

    float wsub[2][4];
    int   bsub[2][4];
#pragma unroll
    for (int q = 0; q < 2; ++q) {
        int j  = tid + q*256;
        if (ww[q] == 0.0f) {
#pragma unroll
            for (int k = 0; k < 4; ++k) wsub[q][k] = 0.0f;
            continue;
        }
        float wb = ww[q] * dinv;
        float d  = dd[q];
        float rc  = fminf(fmaxf(d*3.0f - 0.5f, 0.0f), 2.0f);
        float r0f = floorf(rc);
        float wr  = rc - r0f;
        int r0 = (int)r0f;
        int r1 = min(r0 + 1, 2);
        float rx = (j == ii) ? 1.0f : relx[q];
        float ry = (j == ii) ? 0.0f : rely[q];
        float ang = atan2f(ry, rx);
        if (ang < 0.0f) ang += 6.283185307179586f;
        float tc  = ang * 2.546479089470325f;   // *16/(2*pi)
        float t0f = floorf(tc);
        float wt  = tc - t0f;
        int t0  = ((int)t0f) & 15;              // tc==16 edge -> bin 0 like ref's %16
        int t1i = (t0 + 1) & 15;
        wsub[q][0] = wb * (1.0f-wr) * (1.0f-wt);  bsub[q][0] = r0*16 + t0;
        wsub[q][1] = wb * (1.0f-wr) * wt;         bsub[q][1] = r0*16 + t1i;
        wsub[q][2] = wb * wr * (1.0f-wt);         bsub[q][2] = r1*16 + t0;
        wsub[q][3] = wb * wr * wt;                bsub[q][3] = r1*16 + t1i;
#pragma unroll
        for (int k = 0; k < 4; ++k)
            if (wsub[q][k] != 0.0f) atomicAdd(&bincnt[bsub[q][k]], 1);
    }
    __syncthreads();
    if (tid == 0) {
        int s = 0;
#pragma unroll
        for (int g = 0; g < 48; ++g) { binoff[g] = s; s += bincnt[g]; }
        binoff[48] = s;
    }
    __syncthreads();
    if (tid < 48) binpos[tid] = binoff[tid];
    if (tid < 49) offG[p*64 + tid] = binoff[tid];
    __syncthreads();
#pragma unroll
    for (int q = 0; q < 2; ++q) {
        int j = tid + q*256;
#pragma unroll
        for (int k = 0; k < 4; ++k) {
            if (wsub[q][k] != 0.0f) {
                int slot = atomicAdd(&binpos[bsub[q][k]], 1);
                Ew[p*EMAX + slot] = wsub[q][k];
                Ej[p*EMAX + slot] = (unsigned short)j;
            }
        }
    }
}

// ---------------------------------------------------------------- aggregation: LDS-staged rows
// Block: PT particles x one 64-channel half. Stage ALL 512 batch rows (64 floats each = 128KB)
// into LDS coalesced, plus per-particle packed (w,j) list; entries then read rows from LDS.
// Wave wv handles bins g = wv+8s per particle; per-bin register accumulation, unroll 2.
template<int PT>
__global__ __launch_bounds__(512) void aggregate_kernel(const float* __restrict__ actsrc, int actStride,
                                                        int choff, int C8,
                                                        const float* __restrict__ Ew,
                                                        const unsigned short* __restrict__ Ej,
                                                        const int* __restrict__ offG,
                                                        float* __restrict__ Fbuf, int Krow)
{
    __shared__ float  rows[512*64];      // 128 KB
    __shared__ float2 ebuf[EMAX];        // 16 KB packed (w, j-bits)
    __shared__ int    soff[49];
    int tid  = threadIdx.x;
    int lane = tid & 63;
    int wv   = tid >> 6;                 // 0..7
    int p0   = blockIdx.x * PT;
    int pbase = p0 & ~511;               // batch base (PT divides 512)

    // stage all 512 rows of this batch's channel-half
    {
        float4* r4 = (float4*)rows;
        for (int k = 0; k < 16; ++k) {
            int idx4 = tid + k*512;              // 8192 float4s
            int r = idx4 >> 4, c = (idx4 & 15) * 4;
            r4[idx4] = *(const float4*)(actsrc + (size_t)(pbase + r)*actStride + choff + c);
        }
    }

    for (int pp = 0; pp < PT; ++pp) {
        int p = p0 + pp;
        __syncthreads();                 // rows ready (first iter) / prior particle done
        if (tid < 49) soff[tid] = offG[p*64 + tid];
        __syncthreads();
        int cnt = soff[48];
        for (int i = tid; i < cnt; i += 512) {
            float2 e; e.x = Ew[p*EMAX + i]; e.y = __uint_as_float((unsigned)Ej[p*EMAX + i]);
            ebuf[i] = e;
        }
        __syncthreads();

        float* dst = Fbuf + (size_t)p * Krow + choff + lane;
#pragma unroll
        for (int s = 0; s < 6; ++s) {
            int g = wv + s*8;
            int e0 = soff[g], e1 = soff[g+1];
            float a0 = 0.0f, a1 = 0.0f;
            int e = e0;
            for (; e + 2 <= e1; e += 2) {
                float2 m0 = ebuf[e], m1 = ebuf[e+1];
                int j0 = (int)__float_as_uint(m0.y);
                int j1 = (int)__float_as_uint(m1.y);
                float f0 = rows[j0*64 + lane];
                float f1 = rows[j1*64 + lane];
                a0 = fmaf(m0.x, f0, a0);
                a1 = fmaf(m1.x, f1, a1);
            }
            if (e < e1) {
                float2 m0 = ebuf[e];
                int j0 = (int)__float_as_uint(m0.y);
                a0 = fmaf(m0.x, rows[j0*64 + lane], a0);
            }
            dst[g*C8] = a0 + a1;
        }
    }
}

// ---------------------------------------------------------------- expand weights into B matrices
__global__ void expand_kernel(const float* __restrict__ Wc, const float* __restrict__ Wd,
                              const float* __restrict__ pc4, const float* __restrict__ pd4,
                              float* __restrict__ Bm, int C, int O8, int total, int mode)
{
    int e = blockIdx.x*blockDim.x + threadIdx.x;
    if (e >= total) return;
    int col = e % O8;
    int k   = e / O8;
    int C8  = C*8;
    bool conv = (k < 48*C8);
    int cc, nn, rr = 0, tt = 0;
    if (conv) {
        int g = k / C8, rem = k - g*C8;
        cc = rem >> 3; nn = rem & 7; rr = g >> 4; tt = g & 15;
    } else {
        int rem = k - 48*C8;
        cc = rem >> 3; nn = rem & 7;
    }
    float val = 0.0f;
    if (mode == 0) {
        int o = col >> 3, m = col & 7;
        if (conv) val = Wc[(((o*C + cc)*8 + ((nn - m) & 7))*3 + rr)*16 + ((tt - 2*m) & 15)];
        else      val = Wd[(o*C + cc)*8 + ((m - nn) & 7)];
    } else if (mode == 1) {
        int o = col >> 3, m = col & 7;
        if (col < 32) { if (conv)  val = Wc[(((o*C + cc)*8 + ((nn - m)&7))*3 + rr)*16 + ((tt - 2*m)&15)]; }
        else          { if (!conv) val = Wd[((o-4)*C + cc)*8 + ((m - nn)&7)]; }
    } else {
        if (col < 6) {
            int co = col >> 1, aa = col & 1;
            float s0 = conv ? pc4[0] : pd4[0];
            float s1 = conv ? pc4[1] : pd4[1];
#pragma unroll
            for (int m = 0; m < 8; ++m) {
                float th = (float)m * 0.7853981633974483f;
                float csv = cosf(th), snv = sinf(th);
                float bas = (aa == 0) ? (s0*csv - s1*snv) : (s0*snv + s1*csv);
                float wv;
                if (conv) wv = Wc[(((co*C + cc)*8 + ((nn - m)&7))*3 + rr)*16 + ((tt - 2*m)&15)];
                else      wv = Wd[(co*C + cc)*8 + ((m - nn)&7)];
                val += wv * bas;
            }
        }
    }
    Bm[e] = val;
}

// ---------------------------------------------------------------- split-K register-tiled f32 GEMM
template<int N>
__global__ __launch_bounds__(256) void gemm_tile(const float* __restrict__ A, int Kdim,
                                                 const float* __restrict__ B,
                                                 float* __restrict__ Cpart)
{
    constexpr int CT = N/16;               // 1, 4, 8
    __shared__ float As[32][68];           // k-major [kk][row], padded
    __shared__ float Bs[32][N];
    int tid = threadIdx.x;
    int tr = tid & 15, tc = tid >> 4;
    int m0 = blockIdx.x * 64;
    int k0base = blockIdx.y * 224;
    float acc[4][CT];
#pragma unroll
    for (int i = 0; i < 4; ++i)
#pragma unroll
        for (int u = 0; u < CT; ++u) acc[i][u] = 0.0f;

    int ar = tid >> 2, aq = (tid & 3) * 8;
    for (int k0 = 0; k0 < 224; k0 += 32) {
        const float* Ap = A + (size_t)(m0 + ar)*Kdim + k0base + k0 + aq;
        float4 av0 = *(const float4*)(Ap);
        float4 av1 = *(const float4*)(Ap + 4);
        As[aq+0][ar] = av0.x; As[aq+1][ar] = av0.y; As[aq+2][ar] = av0.z; As[aq+3][ar] = av0.w;
        As[aq+4][ar] = av1.x; As[aq+5][ar] = av1.y; As[aq+6][ar] = av1.z; As[aq+7][ar] = av1.w;
#pragma unroll
        for (int u = 0; u < (8*N + 255)/256; ++u) {
            int idx = tid + 256*u;
            if (idx < 8*N) {
                int row = idx / (N/4), c4 = idx % (N/4);
                *(float4*)&Bs[row][c4*4] = *(const float4*)(B + (size_t)(k0base + k0 + row)*N + c4*4);
            }
        }
        __syncthreads();
#pragma unroll
        for (int kk = 0; kk < 32; ++kk) {
            float4 a4 = *(const float4*)&As[kk][tr*4];
            if (CT == 1) {
                float bv = Bs[kk][tc];
                acc[0][0] += a4.x*bv; acc[1][0] += a4.y*bv;
                acc[2][0] += a4.z*bv; acc[3][0] += a4.w*bv;
            } else {
#pragma unroll
                for (int uu = 0; uu < CT; uu += 4) {
                    float4 b4 = *(const float4*)&Bs[kk][tc*CT + uu];
                    acc[0][uu+0] += a4.x*b4.x; acc[0][uu+1] += a4.x*b4.y; acc[0][uu+2] += a4.x*b4.z; acc[0][uu+3] += a4.x*b4.w;
                    acc[1][uu+0] += a4.y*b4.x; acc[1][uu+1] += a4.y*b4.y; acc[1][uu+2] += a4.y*b4.z; acc[1][uu+3] += a4.y*b4.w;
                    acc[2][uu+0] += a4.z*b4.x; acc[2][uu+1] += a4.z*b4.y; acc[2][uu+2] += a4.z*b4.z; acc[2][uu+3] += a4.z*b4.w;
                    acc[3][uu+0] += a4.w*b4.x; acc[3][uu+1] += a4.w*b4.y; acc[3][uu+2] += a4.w*b4.z; acc[3][uu+3] += a4.w*b4.w;
                }
            }
        }
        __syncthreads();
    }
    float* Cp = Cpart + ((size_t)blockIdx.y*1024 + m0)*N;
#pragma unroll
    for (int i = 0; i < 4; ++i)
#pragma unroll
        for (int u = 0; u < CT; ++u)
            Cp[(size_t)(tr*4 + i)*N + tc*CT + u] = acc[i][u];
}

// ---------------------------------------------------------------- epilogue: split-reduce + residual + mag_act
__global__ void epilogue_kernel(const float* __restrict__ Cpart, int S, int O, int res,
                                float* __restrict__ outBuf, float* __restrict__ actDst, int actStride)
{
    int id = blockIdx.x*blockDim.x + threadIdx.x;
    if (id >= NPART*O) return;
    int p = id / O, c = id % O;
    int O8 = O*8;
    float x[8];
#pragma unroll
    for (int m = 0; m < 8; ++m) x[m] = 0.0f;
    for (int s = 0; s < S; ++s) {
        const float4* q = (const float4*)(Cpart + ((size_t)(s*1024 + p))*O8 + c*8);
        float4 u0 = q[0], u1 = q[1];
        x[0]+=u0.x; x[1]+=u0.y; x[2]+=u0.z; x[3]+=u0.w;
        x[4]+=u1.x; x[5]+=u1.y; x[6]+=u1.z; x[7]+=u1.w;
    }
    float* ob = outBuf + (size_t)p*O8 + c*8;
    float mag = 1e-6f;
#pragma unroll
    for (int m = 0; m < 8; ++m) {
        float v = x[m];
        if (res) v += ob[m];
        x[m] = v; mag += v*v;
    }
#pragma unroll
    for (int m = 0; m < 8; ++m) ob[m] = x[m];
    float sc = fmaxf(mag - 0.2f, 0.0f) / mag;
    float* ad = actDst + (size_t)p*actStride + c*8;
#pragma unroll
    for (int m = 0; m < 8; ++m) ad[m] = x[m]*sc;
}

// ---------------------------------------------------------------- final outputs (S splits, N=16 partials)
__global__ void final_kernel(const float* __restrict__ Cpart, int S, const float* __restrict__ p1,
                             const float* __restrict__ p0, float* __restrict__ out)
{
    int p = blockIdx.x*blockDim.x + threadIdx.x;
    if (p >= NPART) return;
    float c[6];
#pragma unroll
    for (int t = 0; t < 6; ++t) c[t] = 0.0f;
    for (int s = 0; s < S; ++s) {
        const float* q = Cpart + ((size_t)(s*1024 + p))*16;
#pragma unroll
        for (int t = 0; t < 6; ++t) c[t] += q[t];
    }
    const float sc = 0.0078125f;  // 1/128
#pragma unroll
    for (int t = 0; t < 6; ++t) c[t] *= sc;
    float pcx = p1[p*2+0] + c[0], pcy = p1[p*2+1] + c[1];
    out[p*2+0] = pcx; out[p*2+1] = pcy;
    out[2048 + p*2+0] = pcx - p0[p*2+0];
    out[2048 + p*2+1] = pcy - p0[p*2+1];
    out[4096 + p*4+0] = c[2]; out[4096 + p*4+1] = c[3];
    out[4096 + p*4+2] = c[4]; out[4096 + p*4+3] = c[5];
}

// ---------------------------------------------------------------- launch
extern "C" void kernel_launch(void* const* d_in, const int* in_sizes, int n_in,
                              void* d_out, int out_size, void* d_ws, size_t ws_size,
                              hipStream_t stream)
{
    const float* p0_enc  = (const float*)d_in[0];
    const float* v0_enc  = (const float*)d_in[1];
    const float* p0      = (const float*)d_in[2];
    const float* v0      = (const float*)d_in[3];
    const float* a       = (const float*)d_in[4];
    const float* mask    = (const float*)d_in[5];
    const float* lift_c0 = (const float*)d_in[6];
    const float* Wc0     = (const float*)d_in[7];
    const float* lift_d0 = (const float*)d_in[8];
    const float* Wd0     = (const float*)d_in[9];
    const float* Wc1     = (const float*)d_in[10];
    const float* Wd1     = (const float*)d_in[11];
    const float* Wc2     = (const float*)d_in[12];
    const float* Wd2     = (const float*)d_in[13];
    const float* Wc3     = (const float*)d_in[14];
    const float* Wd3     = (const float*)d_in[15];
    const float* Wc4     = (const float*)d_in[16];
    const float* pc4     = (const float*)d_in[17];
    const float* Wd4     = (const float*)d_in[18];
    const float* pd4     = (const float*)d_in[19];
    float* out = (float*)d_out;

    float* wsf    = (float*)d_ws;
    float* featsC = wsf;                               // 131072
    float* p1     = featsC + 131072;                   // 2048
    float* Ew     = p1 + 2048;                         // 1024*2048 = 2097152
    unsigned short* Ej = (unsigned short*)(Ew + 2097152);  // 2097152 ushort = 1048576 floats
    int*   offG   = (int*)(Ew + 2097152 + 1048576);    // 1024*64 = 65536
    float* Fbuf   = (float*)offG + 65536;              // 6422528
    float* Cpart  = Fbuf + 1024*6272;                  // 1835008 (28*1024*64 = 14*1024*128)
    float* outBuf = Cpart + 1835008;                   // 131072
    float* Bm0    = outBuf + 131072;                   // 6272*64
    float* Bm1    = Bm0 + 6272*64;                     // 3136*64
    float* Bm2    = Bm1 + 3136*64;                     // 3136*128
    float* Bm3    = Bm2 + 3136*128;                    // 6272*64
    float* Bm4    = Bm3 + 6272*64;                     // 3136*16

    prep_kernel<<<NPART, 128, 0, stream>>>(p0_enc, v0_enc, p0, v0, a, lift_c0, lift_d0,
                                           featsC, Fbuf, p1);
    pairs_kernel<<<NPART, 256, 0, stream>>>(p1, mask, Ew, Ej, offG);

    {   // expand B matrices
        int t0 = 6272*64;  expand_kernel<<<(t0+255)/256, 256, 0, stream>>>(Wc0, Wd0, pc4, pd4, Bm0, 16,  64, t0, 1);
        int t1 = 3136*64;  expand_kernel<<<(t1+255)/256, 256, 0, stream>>>(Wc1, Wd1, pc4, pd4, Bm1,  8,  64, t1, 0);
        int t2 = 3136*128; expand_kernel<<<(t2+255)/256, 256, 0, stream>>>(Wc2, Wd2, pc4, pd4, Bm2,  8, 128, t2, 0);
        int t3 = 6272*64;  expand_kernel<<<(t3+255)/256, 256, 0, stream>>>(Wc3, Wd3, pc4, pd4, Bm3, 16,  64, t3, 0);
        int t4 = 3136*16;  expand_kernel<<<(t4+255)/256, 256, 0, stream>>>(Wc4, Wd4, pc4, pd4, Bm4,  8,  16, t4, 2);
    }

    // Layer 0  (C8=128, K=6272, S=28): 2 channel-halves
    aggregate_kernel<8><<<dim3(128,1), 512, 0, stream>>>(featsC, 128,  0, 128, Ew, Ej, offG, Fbuf, 6272);
    aggregate_kernel<8><<<dim3(128,1), 512, 0, stream>>>(featsC, 128, 64, 128, Ew, Ej, offG, Fbuf, 6272);
    gemm_tile<64><<<dim3(16,28), 256, 0, stream>>>(Fbuf, 6272, Bm0, Cpart);
    epilogue_kernel<<<(NPART*8+63)/64, 64, 0, stream>>>(Cpart, 28, 8, 0, outBuf, Fbuf + 3072, 3136);
    // Layer 1  (C8=64, K=3136, S=14, residual)
    aggregate_kernel<4><<<dim3(256,1), 512, 0, stream>>>(Fbuf + 3072, 3136, 0, 64, Ew, Ej, offG, Fbuf, 3136);
    gemm_tile<64><<<dim3(16,14), 256, 0, stream>>>(Fbuf, 3136, Bm1, Cpart);
    epilogue_kernel<<<(NPART*8+63)/64, 64, 0, stream>>>(Cpart, 14, 8, 1, outBuf, Fbuf + 3072, 3136);
    // Layer 2  (C8=64 -> O=16, S=14)
    aggregate_kernel<4><<<dim3(256,1), 512, 0, stream>>>(Fbuf + 3072, 3136, 0, 64, Ew, Ej, offG, Fbuf, 3136);
    gemm_tile<128><<<dim3(16,14), 256, 0, stream>>>(Fbuf, 3136, Bm2, Cpart);
    epilogue_kernel<<<(NPART*16+63)/64, 64, 0, stream>>>(Cpart, 14, 16, 0, outBuf, Fbuf + 6144, 6272);
    // Layer 3  (C8=128 -> O=8, S=28)
    aggregate_kernel<8><<<dim3(128,1), 512, 0, stream>>>(Fbuf + 6144, 6272,  0, 128, Ew, Ej, offG, Fbuf, 6272);
    aggregate_kernel<8><<<dim3(128,1), 512, 0, stream>>>(Fbuf + 6144, 6272, 64, 128, Ew, Ej, offG, Fbuf, 6272);
    gemm_tile<64><<<dim3(16,28), 256, 0, stream>>>(Fbuf, 6272, Bm3, Cpart);
    epilogue_kernel<<<(NPART*8+63)/64, 64, 0, stream>>>(Cpart, 28, 8, 0, outBuf, Fbuf + 3072, 3136);
    // Layer 4  (C8=64 -> N=16 padded, proj folded, S=14)
    aggregate_kernel<4><<<dim3(256,1), 512, 0, stream>>>(Fbuf + 3072, 3136, 0, 64, Ew, Ej, offG, Fbuf, 3136);
    gemm_tile<16><<<dim3(16,14), 256, 0, stream>>>(Fbuf, 3136, Bm4, Cpart);
    final_kernel<<<4, 256, 0, stream>>>(Cpart, 14, p1, p0, out);
}

// Round 11
// 457.433 us; speedup vs baseline: 1.3627x; 1.1532x over previous
//
#include <hip/hip_runtime.h>

#define NPART 1024
#define NNB   512
#define EMAX  2048   // max sub-entries per particle (4*512)

// ---------------------------------------------------------------- prep
__global__ void prep_kernel(const float* __restrict__ p0_enc, const float* __restrict__ v0_enc,
                            const float* __restrict__ p0, const float* __restrict__ v0,
                            const float* __restrict__ a, const float* __restrict__ liftc,
                            const float* __restrict__ liftd,
                            float* __restrict__ featsC, float* __restrict__ Fbuf,
                            float* __restrict__ p1out)
{
    int p = blockIdx.x;          // b*N + i
    int t = threadIdx.x;         // 128 threads: c*8 + m
    int c = t >> 3, m = t & 7;
    float v0x = v0[p*2+0], v0y = v0[p*2+1];
    float ax  = a[p*2+0],  ay  = a[p*2+1];
    float p0x = p0[p*2+0], p0y = p0[p*2+1];
    float v1x = v0x + ax, v1y = v0y + ay;
    float p1x = p0x + 0.5f*(v0x + v1x), p1y = p0y + 0.5f*(v0y + v1y);
    float vx, vy;
    if (c == 0)      { vx = v1x; vy = v1y; }
    else if (c == 1) { vx = p1x; vy = p1y; }
    else if (c < 9)  { vx = v0_enc[(p*7 + (c-2))*2+0]; vy = v0_enc[(p*7 + (c-2))*2+1]; }
    else             { vx = p0_enc[(p*7 + (c-9))*2+0]; vy = p0_enc[(p*7 + (c-9))*2+1]; }
    float th = (float)m * 0.7853981633974483f;
    float cs = cosf(th), sn = sinf(th);
    float lc0 = liftc[0], lc1 = liftc[1];
    float ld0 = liftd[0], ld1 = liftd[1];
    featsC[p*128 + t]        = vx*(lc0*cs - lc1*sn) + vy*(lc0*sn + lc1*cs);
    Fbuf[p*6272 + 6144 + t]  = vx*(ld0*cs - ld1*sn) + vy*(ld0*sn + ld1*cs);  // layer-0 dense tail
    if (t == 0) { p1out[p*2+0] = p1x; p1out[p*2+1] = p1y; }
}

// ---------------------------------------------------------------- pair weights -> per-bin bucketed lists
__global__ void pairs_kernel(const float* __restrict__ p1, const float* __restrict__ mask,
                             float* __restrict__ Ew, unsigned short* __restrict__ Ej,
                             int* __restrict__ offG)
{
    int p  = blockIdx.x;          // b*N + i
    int b  = p >> 9;
    int ii = p & 511;
    int tid = threadIdx.x;        // 256
    __shared__ float red[256];
    __shared__ float denomS;
    __shared__ int bincnt[48];
    __shared__ int binoff[49];
    __shared__ int binpos[48];
    if (tid < 48) bincnt[tid] = 0;
    float pix = p1[p*2+0], piy = p1[p*2+1];
    float relx[2], rely[2], dd[2], ww[2];
#pragma unroll
    for (int q = 0; q < 2; ++q) {
        int j  = tid + q*256;
        int jr = b*NNB + j;
        float rx = p1[jr*2+0] - pix;
        float ry = p1[jr*2+1] - piy;
        float d  = sqrtf(rx*rx + ry*ry + 1e-12f) * (1.0f/40.0f);
        float t1 = fmaxf(1.0f - d*d, 0.0f);
        float w  = t1*t1*t1 * mask[jr];
        relx[q] = rx; rely[q] = ry; dd[q] = d; ww[q] = w;
    }
    red[tid] = ww[0] + ww[1];
    __syncthreads();
    for (int s = 128; s > 0; s >>= 1) {
        if (tid < s) red[tid] += red[tid+s];
        __syncthreads();
    }
    if (tid == 0) denomS = 1.0f / (red[0] + 1e-6f);
    __syncthreads();
    float dinv = denomS;

    float wsub[2][4];
    int   bsub[2][4];
#pragma unroll
    for (int q = 0; q < 2; ++q) {
        int j  = tid + q*256;
        if (ww[q] == 0.0f) {
#pragma unroll
            for (int k = 0; k < 4; ++k) wsub[q][k] = 0.0f;
            continue;
        }
        float wb = ww[q] * dinv;
        float d  = dd[q];
        float rc  = fminf(fmaxf(d*3.0f - 0.5f, 0.0f), 2.0f);
        float r0f = floorf(rc);
        float wr  = rc - r0f;
        int r0 = (int)r0f;
        int r1 = min(r0 + 1, 2);
        float rx = (j == ii) ? 1.0f : relx[q];
        float ry = (j == ii) ? 0.0f : rely[q];
        float ang = atan2f(ry, rx);
        if (ang < 0.0f) ang += 6.283185307179586f;
        float tc  = ang * 2.546479089470325f;   // *16/(2*pi)
        float t0f = floorf(tc);
        float wt  = tc - t0f;
        int t0  = ((int)t0f) & 15;              // tc==16 edge -> bin 0 like ref's %16
        int t1i = (t0 + 1) & 15;
        wsub[q][0] = wb * (1.0f-wr) * (1.0f-wt);  bsub[q][0] = r0*16 + t0;
        wsub[q][1] = wb * (1.0f-wr) * wt;         bsub[q][1] = r0*16 + t1i;
        wsub[q][2] = wb * wr * (1.0f-wt);         bsub[q][2] = r1*16 + t0;
        wsub[q][3] = wb * wr * wt;                bsub[q][3] = r1*16 + t1i;
#pragma unroll
        for (int k = 0; k < 4; ++k)
            if (wsub[q][k] != 0.0f) atomicAdd(&bincnt[bsub[q][k]], 1);
    }
    __syncthreads();
    if (tid == 0) {
        int s = 0;
#pragma unroll
        for (int g = 0; g < 48; ++g) { binoff[g] = s; s += bincnt[g]; }
        binoff[48] = s;
    }
    __syncthreads();
    if (tid < 48) binpos[tid] = binoff[tid];
    if (tid < 49) offG[p*64 + tid] = binoff[tid];
    __syncthreads();
#pragma unroll
    for (int q = 0; q < 2; ++q) {
        int j = tid + q*256;
#pragma unroll
        for (int k = 0; k < 4; ++k) {
            if (wsub[q][k] != 0.0f) {
                int slot = atomicAdd(&binpos[bsub[q][k]], 1);
                Ew[p*EMAX + slot] = wsub[q][k];
                Ej[p*EMAX + slot] = (unsigned short)j;
            }
        }
    }
}

// masked quad meta load from ebuf (w=0 for tail, j clamped to e0's j -> safe row idx)
#define LMQ(B, W0,W1,W2,W3, J0,J1,J2,J3) do {                                              \
    int _b = (B);                                                                          \
    { int _q=_b+0; bool _v=_q<len; float2 _m=ebuf[_v? e0+_q : e0]; W0=_v?_m.x:0.0f; J0=(int)__float_as_uint(_m.y); } \
    { int _q=_b+1; bool _v=_q<len; float2 _m=ebuf[_v? e0+_q : e0]; W1=_v?_m.x:0.0f; J1=(int)__float_as_uint(_m.y); } \
    { int _q=_b+2; bool _v=_q<len; float2 _m=ebuf[_v? e0+_q : e0]; W2=_v?_m.x:0.0f; J2=(int)__float_as_uint(_m.y); } \
    { int _q=_b+3; bool _v=_q<len; float2 _m=ebuf[_v? e0+_q : e0]; W3=_v?_m.x:0.0f; J3=(int)__float_as_uint(_m.y); } \
} while(0)

// ---------------------------------------------------------------- aggregation: LDS-staged rows, quad-pipelined
// Block: PT particles x one 64-channel half (choff = blockIdx.y*64). All 512 batch rows staged in LDS.
// Wave wv handles bins g = wv+8s. Entries processed in quads of 4 with meta 2-ahead, rows 1-ahead.
template<int PT>
__global__ __launch_bounds__(512) void aggregate_kernel(const float* __restrict__ actsrc, int actStride,
                                                        int C8,
                                                        const float* __restrict__ Ew,
                                                        const unsigned short* __restrict__ Ej,
                                                        const int* __restrict__ offG,
                                                        float* __restrict__ Fbuf, int Krow)
{
    __shared__ float  rows[512*64];      // 128 KB
    __shared__ float2 ebuf[EMAX];        // 16 KB packed (w, j-bits)
    __shared__ int    soff[49];
    int tid  = threadIdx.x;
    int lane = tid & 63;
    int wv   = tid >> 6;                 // 0..7
    int choff = blockIdx.y * 64;
    int p0   = blockIdx.x * PT;
    int pbase = p0 & ~511;               // batch base (PT divides 512)

    {   // stage all 512 rows of this batch's channel-half (coalesced)
        float4* r4 = (float4*)rows;
#pragma unroll
        for (int k = 0; k < 16; ++k) {
            int idx4 = tid + k*512;              // 8192 float4s
            int r = idx4 >> 4, c = (idx4 & 15) * 4;
            r4[idx4] = *(const float4*)(actsrc + (size_t)(pbase + r)*actStride + choff + c);
        }
    }

    for (int pp = 0; pp < PT; ++pp) {
        int p = p0 + pp;
        __syncthreads();                 // rows ready / prior particle done
        if (tid < 49) soff[tid] = offG[p*64 + tid];
        __syncthreads();
        int cnt = soff[48];
        for (int i = tid; i < cnt; i += 512) {
            float2 e; e.x = Ew[p*EMAX + i]; e.y = __uint_as_float((unsigned)Ej[p*EMAX + i]);
            ebuf[i] = e;
        }
        __syncthreads();

        float* dst = Fbuf + (size_t)p * Krow + choff + lane;
#pragma unroll
        for (int s = 0; s < 6; ++s) {
            int g = wv + s*8;
            int e0 = soff[g], e1 = soff[g+1];
            int len = e1 - e0;
            float a0 = 0.0f, a1 = 0.0f, a2 = 0.0f, a3 = 0.0f;
            if (len > 0) {
                int nq = (len + 3) >> 2;
                float wa0,wa1,wa2,wa3, wb0,wb1,wb2,wb3;
                int   ja0,ja1,ja2,ja3, jb0,jb1,jb2,jb3;
                LMQ(0, wa0,wa1,wa2,wa3, ja0,ja1,ja2,ja3);
                float fa0 = rows[ja0*64 + lane];
                float fa1 = rows[ja1*64 + lane];
                float fa2 = rows[ja2*64 + lane];
                float fa3 = rows[ja3*64 + lane];
                LMQ(4, wb0,wb1,wb2,wb3, jb0,jb1,jb2,jb3);
                for (int iq = 0; iq < nq; ++iq) {
                    float wc0,wc1,wc2,wc3; int jc0,jc1,jc2,jc3;
                    LMQ((iq+2)*4, wc0,wc1,wc2,wc3, jc0,jc1,jc2,jc3);
                    float fb0 = rows[jb0*64 + lane];
                    float fb1 = rows[jb1*64 + lane];
                    float fb2 = rows[jb2*64 + lane];
                    float fb3 = rows[jb3*64 + lane];
                    a0 = fmaf(wa0, fa0, a0);
                    a1 = fmaf(wa1, fa1, a1);
                    a2 = fmaf(wa2, fa2, a2);
                    a3 = fmaf(wa3, fa3, a3);
                    wa0=wb0; wa1=wb1; wa2=wb2; wa3=wb3;
                    fa0=fb0; fa1=fb1; fa2=fb2; fa3=fb3;
                    wb0=wc0; wb1=wc1; wb2=wc2; wb3=wc3;
                    jb0=jc0; jb1=jc1; jb2=jc2; jb3=jc3;
                }
            }
            dst[g*C8] = (a0 + a1) + (a2 + a3);
        }
    }
}

// ---------------------------------------------------------------- expand weights into B matrices
__global__ void expand_kernel(const float* __restrict__ Wc, const float* __restrict__ Wd,
                              const float* __restrict__ pc4, const float* __restrict__ pd4,
                              float* __restrict__ Bm, int C, int O8, int total, int mode)
{
    int e = blockIdx.x*blockDim.x + threadIdx.x;
    if (e >= total) return;
    int col = e % O8;
    int k   = e / O8;
    int C8  = C*8;
    bool conv = (k < 48*C8);
    int cc, nn, rr = 0, tt = 0;
    if (conv) {
        int g = k / C8, rem = k - g*C8;
        cc = rem >> 3; nn = rem & 7; rr = g >> 4; tt = g & 15;
    } else {
        int rem = k - 48*C8;
        cc = rem >> 3; nn = rem & 7;
    }
    float val = 0.0f;
    if (mode == 0) {
        int o = col >> 3, m = col & 7;
        if (conv) val = Wc[(((o*C + cc)*8 + ((nn - m) & 7))*3 + rr)*16 + ((tt - 2*m) & 15)];
        else      val = Wd[(o*C + cc)*8 + ((m - nn) & 7)];
    } else if (mode == 1) {
        int o = col >> 3, m = col & 7;
        if (col < 32) { if (conv)  val = Wc[(((o*C + cc)*8 + ((nn - m)&7))*3 + rr)*16 + ((tt - 2*m)&15)]; }
        else          { if (!conv) val = Wd[((o-4)*C + cc)*8 + ((m - nn)&7)]; }
    } else {
        if (col < 6) {
            int co = col >> 1, aa = col & 1;
            float s0 = conv ? pc4[0] : pd4[0];
            float s1 = conv ? pc4[1] : pd4[1];
#pragma unroll
            for (int m = 0; m < 8; ++m) {
                float th = (float)m * 0.7853981633974483f;
                float csv = cosf(th), snv = sinf(th);
                float bas = (aa == 0) ? (s0*csv - s1*snv) : (s0*snv + s1*csv);
                float wv;
                if (conv) wv = Wc[(((co*C + cc)*8 + ((nn - m)&7))*3 + rr)*16 + ((tt - 2*m)&15)];
                else      wv = Wd[(co*C + cc)*8 + ((m - nn)&7)];
                val += wv * bas;
            }
        }
    }
    Bm[e] = val;
}

// ---------------------------------------------------------------- split-K register-tiled f32 GEMM
template<int N>
__global__ __launch_bounds__(256) void gemm_tile(const float* __restrict__ A, int Kdim,
                                                 const float* __restrict__ B,
                                                 float* __restrict__ Cpart)
{
    constexpr int CT = N/16;               // 1, 4, 8
    __shared__ float As[32][68];           // k-major [kk][row], padded
    __shared__ float Bs[32][N];
    int tid = threadIdx.x;
    int tr = tid & 15, tc = tid >> 4;
    int m0 = blockIdx.x * 64;
    int k0base = blockIdx.y * 224;
    float acc[4][CT];
#pragma unroll
    for (int i = 0; i < 4; ++i)
#pragma unroll
        for (int u = 0; u < CT; ++u) acc[i][u] = 0.0f;

    int ar = tid >> 2, aq = (tid & 3) * 8;
    for (int k0 = 0; k0 < 224; k0 += 32) {
        const float* Ap = A + (size_t)(m0 + ar)*Kdim + k0base + k0 + aq;
        float4 av0 = *(const float4*)(Ap);
        float4 av1 = *(const float4*)(Ap + 4);
        As[aq+0][ar] = av0.x; As[aq+1][ar] = av0.y; As[aq+2][ar] = av0.z; As[aq+3][ar] = av0.w;
        As[aq+4][ar] = av1.x; As[aq+5][ar] = av1.y; As[aq+6][ar] = av1.z; As[aq+7][ar] = av1.w;
#pragma unroll
        for (int u = 0; u < (8*N + 255)/256; ++u) {
            int idx = tid + 256*u;
            if (idx < 8*N) {
                int row = idx / (N/4), c4 = idx % (N/4);
                *(float4*)&Bs[row][c4*4] = *(const float4*)(B + (size_t)(k0base + k0 + row)*N + c4*4);
            }
        }
        __syncthreads();
#pragma unroll
        for (int kk = 0; kk < 32; ++kk) {
            float4 a4 = *(const float4*)&As[kk][tr*4];
            if (CT == 1) {
                float bv = Bs[kk][tc];
                acc[0][0] += a4.x*bv; acc[1][0] += a4.y*bv;
                acc[2][0] += a4.z*bv; acc[3][0] += a4.w*bv;
            } else {
#pragma unroll
                for (int uu = 0; uu < CT; uu += 4) {
                    float4 b4 = *(const float4*)&Bs[kk][tc*CT + uu];
                    acc[0][uu+0] += a4.x*b4.x; acc[0][uu+1] += a4.x*b4.y; acc[0][uu+2] += a4.x*b4.z; acc[0][uu+3] += a4.x*b4.w;
                    acc[1][uu+0] += a4.y*b4.x; acc[1][uu+1] += a4.y*b4.y; acc[1][uu+2] += a4.y*b4.z; acc[1][uu+3] += a4.y*b4.w;
                    acc[2][uu+0] += a4.z*b4.x; acc[2][uu+1] += a4.z*b4.y; acc[2][uu+2] += a4.z*b4.z; acc[2][uu+3] += a4.z*b4.w;
                    acc[3][uu+0] += a4.w*b4.x; acc[3][uu+1] += a4.w*b4.y; acc[3][uu+2] += a4.w*b4.z; acc[3][uu+3] += a4.w*b4.w;
                }
            }
        }
        __syncthreads();
    }
    float* Cp = Cpart + ((size_t)blockIdx.y*1024 + m0)*N;
#pragma unroll
    for (int i = 0; i < 4; ++i)
#pragma unroll
        for (int u = 0; u < CT; ++u)
            Cp[(size_t)(tr*4 + i)*N + tc*CT + u] = acc[i][u];
}

// ---------------------------------------------------------------- epilogue: split-reduce + residual + mag_act
__global__ void epilogue_kernel(const float* __restrict__ Cpart, int S, int O, int res,
                                float* __restrict__ outBuf, float* __restrict__ actDst, int actStride)
{
    int id = blockIdx.x*blockDim.x + threadIdx.x;
    if (id >= NPART*O) return;
    int p = id / O, c = id % O;
    int O8 = O*8;
    float x[8];
#pragma unroll
    for (int m = 0; m < 8; ++m) x[m] = 0.0f;
    for (int s = 0; s < S; ++s) {
        const float4* q = (const float4*)(Cpart + ((size_t)(s*1024 + p))*O8 + c*8);
        float4 u0 = q[0], u1 = q[1];
        x[0]+=u0.x; x[1]+=u0.y; x[2]+=u0.z; x[3]+=u0.w;
        x[4]+=u1.x; x[5]+=u1.y; x[6]+=u1.z; x[7]+=u1.w;
    }
    float* ob = outBuf + (size_t)p*O8 + c*8;
    float mag = 1e-6f;
#pragma unroll
    for (int m = 0; m < 8; ++m) {
        float v = x[m];
        if (res) v += ob[m];
        x[m] = v; mag += v*v;
    }
#pragma unroll
    for (int m = 0; m < 8; ++m) ob[m] = x[m];
    float sc = fmaxf(mag - 0.2f, 0.0f) / mag;
    float* ad = actDst + (size_t)p*actStride + c*8;
#pragma unroll
    for (int m = 0; m < 8; ++m) ad[m] = x[m]*sc;
}

// ---------------------------------------------------------------- final outputs (S splits, N=16 partials)
__global__ void final_kernel(const float* __restrict__ Cpart, int S, const float* __restrict__ p1,
                             const float* __restrict__ p0, float* __restrict__ out)
{
    int p = blockIdx.x*blockDim.x + threadIdx.x;
    if (p >= NPART) return;
    float c[6];
#pragma unroll
    for (int t = 0; t < 6; ++t) c[t] = 0.0f;
    for (int s = 0; s < S; ++s) {
        const float* q = Cpart + ((size_t)(s*1024 + p))*16;
#pragma unroll
        for (int t = 0; t < 6; ++t) c[t] += q[t];
    }
    const float sc = 0.0078125f;  // 1/128
#pragma unroll
    for (int t = 0; t < 6; ++t) c[t] *= sc;
    float pcx = p1[p*2+0] + c[0], pcy = p1[p*2+1] + c[1];
    out[p*2+0] = pcx; out[p*2+1] = pcy;
    out[2048 + p*2+0] = pcx - p0[p*2+0];
    out[2048 + p*2+1] = pcy - p0[p*2+1];
    out[4096 + p*4+0] = c[2]; out[4096 + p*4+1] = c[3];
    out[4096 + p*4+2] = c[4]; out[4096 + p*4+3] = c[5];
}

// ---------------------------------------------------------------- launch
extern "C" void kernel_launch(void* const* d_in, const int* in_sizes, int n_in,
                              void* d_out, int out_size, void* d_ws, size_t ws_size,
                              hipStream_t stream)
{
    const float* p0_enc  = (const float*)d_in[0];
    const float* v0_enc  = (const float*)d_in[1];
    const float* p0      = (const float*)d_in[2];
    const float* v0      = (const float*)d_in[3];
    const float* a       = (const float*)d_in[4];
    const float* mask    = (const float*)d_in[5];
    const float* lift_c0 = (const float*)d_in[6];
    const float* Wc0     = (const float*)d_in[7];
    const float* lift_d0 = (const float*)d_in[8];
    const float* Wd0     = (const float*)d_in[9];
    const float* Wc1     = (const float*)d_in[10];
    const float* Wd1     = (const float*)d_in[11];
    const float* Wc2     = (const float*)d_in[12];
    const float* Wd2     = (const float*)d_in[13];
    const float* Wc3     = (const float*)d_in[14];
    const float* Wd3     = (const float*)d_in[15];
    const float* Wc4     = (const float*)d_in[16];
    const float* pc4     = (const float*)d_in[17];
    const float* Wd4     = (const float*)d_in[18];
    const float* pd4     = (const float*)d_in[19];
    float* out = (float*)d_out;

    float* wsf    = (float*)d_ws;
    float* featsC = wsf;                               // 131072
    float* p1     = featsC + 131072;                   // 2048
    float* Ew     = p1 + 2048;                         // 1024*2048 = 2097152
    unsigned short* Ej = (unsigned short*)(Ew + 2097152);  // 2097152 ushort = 1048576 floats
    int*   offG   = (int*)(Ew + 2097152 + 1048576);    // 1024*64 = 65536
    float* Fbuf   = (float*)offG + 65536;              // 6422528
    float* Cpart  = Fbuf + 1024*6272;                  // 1835008 (28*1024*64 = 14*1024*128)
    float* outBuf = Cpart + 1835008;                   // 131072
    float* Bm0    = outBuf + 131072;                   // 6272*64
    float* Bm1    = Bm0 + 6272*64;                     // 3136*64
    float* Bm2    = Bm1 + 3136*64;                     // 3136*128
    float* Bm3    = Bm2 + 3136*128;                    // 6272*64
    float* Bm4    = Bm3 + 6272*64;                     // 3136*16

    prep_kernel<<<NPART, 128, 0, stream>>>(p0_enc, v0_enc, p0, v0, a, lift_c0, lift_d0,
                                           featsC, Fbuf, p1);
    pairs_kernel<<<NPART, 256, 0, stream>>>(p1, mask, Ew, Ej, offG);

    {   // expand B matrices
        int t0 = 6272*64;  expand_kernel<<<(t0+255)/256, 256, 0, stream>>>(Wc0, Wd0, pc4, pd4, Bm0, 16,  64, t0, 1);
        int t1 = 3136*64;  expand_kernel<<<(t1+255)/256, 256, 0, stream>>>(Wc1, Wd1, pc4, pd4, Bm1,  8,  64, t1, 0);
        int t2 = 3136*128; expand_kernel<<<(t2+255)/256, 256, 0, stream>>>(Wc2, Wd2, pc4, pd4, Bm2,  8, 128, t2, 0);
        int t3 = 6272*64;  expand_kernel<<<(t3+255)/256, 256, 0, stream>>>(Wc3, Wd3, pc4, pd4, Bm3, 16,  64, t3, 0);
        int t4 = 3136*16;  expand_kernel<<<(t4+255)/256, 256, 0, stream>>>(Wc4, Wd4, pc4, pd4, Bm4,  8,  16, t4, 2);
    }

    // Layer 0  (C8=128, K=6272, S=28): both channel-halves in one dispatch (blockIdx.y)
    aggregate_kernel<8><<<dim3(128,2), 512, 0, stream>>>(featsC, 128, 128, Ew, Ej, offG, Fbuf, 6272);
    gemm_tile<64><<<dim3(16,28), 256, 0, stream>>>(Fbuf, 6272, Bm0, Cpart);
    epilogue_kernel<<<(NPART*8+63)/64, 64, 0, stream>>>(Cpart, 28, 8, 0, outBuf, Fbuf + 3072, 3136);
    // Layer 1  (C8=64, K=3136, S=14, residual)
    aggregate_kernel<4><<<dim3(256,1), 512, 0, stream>>>(Fbuf + 3072, 3136, 64, Ew, Ej, offG, Fbuf, 3136);
    gemm_tile<64><<<dim3(16,14), 256, 0, stream>>>(Fbuf, 3136, Bm1, Cpart);
    epilogue_kernel<<<(NPART*8+63)/64, 64, 0, stream>>>(Cpart, 14, 8, 1, outBuf, Fbuf + 3072, 3136);
    // Layer 2  (C8=64 -> O=16, S=14)
    aggregate_kernel<4><<<dim3(256,1), 512, 0, stream>>>(Fbuf + 3072, 3136, 64, Ew, Ej, offG, Fbuf, 3136);
    gemm_tile<128><<<dim3(16,14), 256, 0, stream>>>(Fbuf, 3136, Bm2, Cpart);
    epilogue_kernel<<<(NPART*16+63)/64, 64, 0, stream>>>(Cpart, 14, 16, 0, outBuf, Fbuf + 6144, 6272);
    // Layer 3  (C8=128 -> O=8, S=28)
    aggregate_kernel<8><<<dim3(128,2), 512, 0, stream>>>(Fbuf + 6144, 6272, 128, Ew, Ej, offG, Fbuf, 6272);
    gemm_tile<64><<<dim3(16,28), 256, 0, stream>>>(Fbuf, 6272, Bm3, Cpart);
    epilogue_kernel<<<(NPART*8+63)/64, 64, 0, stream>>>(Cpart, 28, 8, 0, outBuf, Fbuf + 3072, 3136);
    // Layer 4  (C8=64 -> N=16 padded, proj folded, S=14)
    aggregate_kernel<4><<<dim3(256,1), 512, 0, stream>>>(Fbuf + 3072, 3136, 64, Ew, Ej, offG, Fbuf, 3136);
    gemm_tile<16><<<dim3(16,14), 256, 0, stream>>>(Fbuf, 3136, Bm4, Cpart);
    final_kernel<<<4, 256, 0, stream>>>(Cpart, 14, p1, p0, out);
}

// Round 14
// 395.544 us; speedup vs baseline: 1.5759x; 1.1565x over previous
//
#include <hip/hip_runtime.h>

#define NPART 1024
#define NNB   512
#define EMAX  2048   // max sub-entries per particle (4*512)

// ---------------------------------------------------------------- prep
__global__ void prep_kernel(const float* __restrict__ p0_enc, const float* __restrict__ v0_enc,
                            const float* __restrict__ p0, const float* __restrict__ v0,
                            const float* __restrict__ a, const float* __restrict__ liftc,
                            const float* __restrict__ liftd,
                            float* __restrict__ featsC, float* __restrict__ Fbuf,
                            float* __restrict__ p1out)
{
    int p = blockIdx.x;          // b*N + i
    int t = threadIdx.x;         // 128 threads: c*8 + m
    int c = t >> 3, m = t & 7;
    float v0x = v0[p*2+0], v0y = v0[p*2+1];
    float ax  = a[p*2+0],  ay  = a[p*2+1];
    float p0x = p0[p*2+0], p0y = p0[p*2+1];
    float v1x = v0x + ax, v1y = v0y + ay;
    float p1x = p0x + 0.5f*(v0x + v1x), p1y = p0y + 0.5f*(v0y + v1y);
    float vx, vy;
    if (c == 0)      { vx = v1x; vy = v1y; }
    else if (c == 1) { vx = p1x; vy = p1y; }
    else if (c < 9)  { vx = v0_enc[(p*7 + (c-2))*2+0]; vy = v0_enc[(p*7 + (c-2))*2+1]; }
    else             { vx = p0_enc[(p*7 + (c-9))*2+0]; vy = p0_enc[(p*7 + (c-9))*2+1]; }
    float th = (float)m * 0.7853981633974483f;
    float cs = cosf(th), sn = sinf(th);
    float lc0 = liftc[0], lc1 = liftc[1];
    float ld0 = liftd[0], ld1 = liftd[1];
    featsC[p*128 + t]        = vx*(lc0*cs - lc1*sn) + vy*(lc0*sn + lc1*cs);
    Fbuf[p*6272 + 6144 + t]  = vx*(ld0*cs - ld1*sn) + vy*(ld0*sn + ld1*cs);  // layer-0 dense tail
    if (t == 0) { p1out[p*2+0] = p1x; p1out[p*2+1] = p1y; }
}

// ---------------------------------------------------------------- pair weights -> per-bin bucketed lists
__global__ void pairs_kernel(const float* __restrict__ p1, const float* __restrict__ mask,
                             float* __restrict__ Ew, unsigned short* __restrict__ Ej,
                             int* __restrict__ offG)
{
    int p  = blockIdx.x;          // b*N + i
    int b  = p >> 9;
    int ii = p & 511;
    int tid = threadIdx.x;        // 256
    __shared__ float red[256];
    __shared__ float denomS;
    __shared__ int bincnt[48];
    __shared__ int binoff[49];
    __shared__ int binpos[48];
    if (tid < 48) bincnt[tid] = 0;
    float pix = p1[p*2+0], piy = p1[p*2+1];
    float relx[2], rely[2], dd[2], ww[2];
#pragma unroll
    for (int q = 0; q < 2; ++q) {
        int j  = tid + q*256;
        int jr = b*NNB + j;
        float rx = p1[jr*2+0] - pix;
        float ry = p1[jr*2+1] - piy;
        float d  = sqrtf(rx*rx + ry*ry + 1e-12f) * (1.0f/40.0f);
        float t1 = fmaxf(1.0f - d*d, 0.0f);
        float w  = t1*t1*t1 * mask[jr];
        relx[q] = rx; rely[q] = ry; dd[q] = d; ww[q] = w;
    }
    red[tid] = ww[0] + ww[1];
    __syncthreads();
    for (int s = 128; s > 0; s >>= 1) {
        if (tid < s) red[tid] += red[tid+s];
        __syncthreads();
    }
    if (tid == 0) denomS = 1.0f / (red[0] + 1e-6f);
    __syncthreads();
    float dinv = denomS;

    float wsub[2][4];
    int   bsub[2][4];
#pragma unroll
    for (int q = 0; q < 2; ++q) {
        int j  = tid + q*256;
        if (ww[q] == 0.0f) {
#pragma unroll
            for (int k = 0; k < 4; ++k) wsub[q][k] = 0.0f;
            continue;
        }
        float wb = ww[q] * dinv;
        float d  = dd[q];
        float rc  = fminf(fmaxf(d*3.0f - 0.5f, 0.0f), 2.0f);
        float r0f = floorf(rc);
        float wr  = rc - r0f;
        int r0 = (int)r0f;
        int r1 = min(r0 + 1, 2);
        float rx = (j == ii) ? 1.0f : relx[q];
        float ry = (j == ii) ? 0.0f : rely[q];
        float ang = atan2f(ry, rx);
        if (ang < 0.0f) ang += 6.283185307179586f;
        float tc  = ang * 2.546479089470325f;   // *16/(2*pi)
        float t0f = floorf(tc);
        float wt  = tc - t0f;
        int t0  = ((int)t0f) & 15;              // tc==16 edge -> bin 0 like ref's %16
        int t1i = (t0 + 1) & 15;
        wsub[q][0] = wb * (1.0f-wr) * (1.0f-wt);  bsub[q][0] = r0*16 + t0;
        wsub[q][1] = wb * (1.0f-wr) * wt;         bsub[q][1] = r0*16 + t1i;
        wsub[q][2] = wb * wr * (1.0f-wt);         bsub[q][2] = r1*16 + t0;
        wsub[q][3] = wb * wr * wt;                bsub[q][3] = r1*16 + t1i;
#pragma unroll
        for (int k = 0; k < 4; ++k)
            if (wsub[q][k] != 0.0f) atomicAdd(&bincnt[bsub[q][k]], 1);
    }
    __syncthreads();
    if (tid == 0) {
        int s = 0;
#pragma unroll
        for (int g = 0; g < 48; ++g) { binoff[g] = s; s += bincnt[g]; }
        binoff[48] = s;
    }
    __syncthreads();
    if (tid < 48) binpos[tid] = binoff[tid];
    if (tid < 49) offG[p*64 + tid] = binoff[tid];
    __syncthreads();
#pragma unroll
    for (int q = 0; q < 2; ++q) {
        int j = tid + q*256;
#pragma unroll
        for (int k = 0; k < 4; ++k) {
            if (wsub[q][k] != 0.0f) {
                int slot = atomicAdd(&binpos[bsub[q][k]], 1);
                Ew[p*EMAX + slot] = wsub[q][k];
                Ej[p*EMAX + slot] = (unsigned short)j;
            }
        }
    }
}

// ---------------------------------------------------------------- aggregation: LDS rows, 4-entry lane-group vectorized
// Block: PT particles x one 64-channel half (choff = blockIdx.y*64). All 512 rows staged in LDS
// (stride 68 floats to spread banks). Wave wv owns bins g = wv+8s. Lane = slot*16 + c4:
// 16-lane group 'slot' processes one entry, reading 4 channels (float4) per lane.
// One ds_read_b64 (meta, per-group addr) + one ds_read_b128 (rows) per 4 entries, 2-deep pipeline.
// Per-bin epilogue: shfl_xor(16,32) cross-slot reduce, lanes<16 write float4.
template<int PT>
__global__ __launch_bounds__(512) void aggregate_kernel(const float* __restrict__ actsrc, int actStride,
                                                        int C8,
                                                        const float* __restrict__ Ew,
                                                        const unsigned short* __restrict__ Ej,
                                                        const int* __restrict__ offG,
                                                        float* __restrict__ Fbuf, int Krow)
{
    __shared__ float  rows[512*68];      // 139,264 B (stride 17 float4)
    __shared__ float2 ebuf[EMAX];        // 16 KB packed (w, j-bits)
    __shared__ int    soff[49];
    int tid  = threadIdx.x;
    int lane = tid & 63;
    int wv   = tid >> 6;                 // 0..7
    int slot = lane >> 4;                // 0..3  (entry slot within wave)
    int c4   = lane & 15;                // float4 column (channels c4*4..c4*4+3)
    int choff = blockIdx.y * 64;
    int p0   = blockIdx.x * PT;
    int pbase = p0 & ~511;               // batch base (PT divides 512)

    {   // stage all 512 rows of this batch's channel-half (coalesced)
        float4* r4 = (float4*)rows;
#pragma unroll
        for (int k = 0; k < 16; ++k) {
            int idx4 = tid + k*512;              // 8192 float4s
            int r = idx4 >> 4, q = idx4 & 15;
            r4[r*17 + q] = *(const float4*)(actsrc + (size_t)(pbase + r)*actStride + choff + q*4);
        }
    }
    const float4* rowf4 = (const float4*)rows;

    for (int pp = 0; pp < PT; ++pp) {
        int p = p0 + pp;
        __syncthreads();                 // rows ready / prior particle done
        if (tid < 49) soff[tid] = offG[p*64 + tid];
        __syncthreads();
        int cnt = soff[48];
        for (int i = tid; i < cnt; i += 512) {
            float2 e; e.x = Ew[p*EMAX + i]; e.y = __uint_as_float((unsigned)Ej[p*EMAX + i]);
            ebuf[i] = e;
        }
        __syncthreads();

        float* dst = Fbuf + (size_t)p * Krow + choff;
#pragma unroll
        for (int s = 0; s < 6; ++s) {
            int g = wv + s*8;
            int e0 = soff[g], e1 = soff[g+1];
            int len = e1 - e0;
            float4 acc = make_float4(0.f, 0.f, 0.f, 0.f);
            if (len > 0) {
                int nq = (len + 3) >> 2;
                float wA, wB; float4 fA, fB;
                {   // group 0
                    int qo = slot; bool v = qo < len; int em = v ? (e0 + qo) : e0;
                    float2 m = ebuf[em];
                    wA = v ? m.x : 0.0f;
                    int j = (int)__float_as_uint(m.y);
                    fA = rowf4[j*17 + c4];
                }
                {   // group 1
                    int qo = 4 + slot; bool v = qo < len; int em = v ? (e0 + qo) : e0;
                    float2 m = ebuf[em];
                    wB = v ? m.x : 0.0f;
                    int j = (int)__float_as_uint(m.y);
                    fB = rowf4[j*17 + c4];
                }
                for (int iq = 0; iq < nq; ++iq) {
                    float4 f = fA; float w = wA;
                    fA = fB; wA = wB;
                    int qo = (iq + 2)*4 + slot;
                    bool v = qo < len; int em = v ? (e0 + qo) : e0;
                    float2 m = ebuf[em];
                    wB = v ? m.x : 0.0f;
                    int j = (int)__float_as_uint(m.y);
                    fB = rowf4[j*17 + c4];
                    acc.x = fmaf(w, f.x, acc.x);
                    acc.y = fmaf(w, f.y, acc.y);
                    acc.z = fmaf(w, f.z, acc.z);
                    acc.w = fmaf(w, f.w, acc.w);
                }
            }
            // cross-slot reduction (slot bits are lane bits 4,5)
            acc.x += __shfl_xor(acc.x, 16, 64); acc.x += __shfl_xor(acc.x, 32, 64);
            acc.y += __shfl_xor(acc.y, 16, 64); acc.y += __shfl_xor(acc.y, 32, 64);
            acc.z += __shfl_xor(acc.z, 16, 64); acc.z += __shfl_xor(acc.z, 32, 64);
            acc.w += __shfl_xor(acc.w, 16, 64); acc.w += __shfl_xor(acc.w, 32, 64);
            if (slot == 0) *(float4*)(dst + g*C8 + c4*4) = acc;
        }
    }
}

// ---------------------------------------------------------------- expand weights into B matrices
__global__ void expand_kernel(const float* __restrict__ Wc, const float* __restrict__ Wd,
                              const float* __restrict__ pc4, const float* __restrict__ pd4,
                              float* __restrict__ Bm, int C, int O8, int total, int mode)
{
    int e = blockIdx.x*blockDim.x + threadIdx.x;
    if (e >= total) return;
    int col = e % O8;
    int k   = e / O8;
    int C8  = C*8;
    bool conv = (k < 48*C8);
    int cc, nn, rr = 0, tt = 0;
    if (conv) {
        int g = k / C8, rem = k - g*C8;
        cc = rem >> 3; nn = rem & 7; rr = g >> 4; tt = g & 15;
    } else {
        int rem = k - 48*C8;
        cc = rem >> 3; nn = rem & 7;
    }
    float val = 0.0f;
    if (mode == 0) {
        int o = col >> 3, m = col & 7;
        if (conv) val = Wc[(((o*C + cc)*8 + ((nn - m) & 7))*3 + rr)*16 + ((tt - 2*m) & 15)];
        else      val = Wd[(o*C + cc)*8 + ((m - nn) & 7)];
    } else if (mode == 1) {
        int o = col >> 3, m = col & 7;
        if (col < 32) { if (conv)  val = Wc[(((o*C + cc)*8 + ((nn - m)&7))*3 + rr)*16 + ((tt - 2*m)&15)]; }
        else          { if (!conv) val = Wd[((o-4)*C + cc)*8 + ((m - nn)&7)]; }
    } else {
        if (col < 6) {
            int co = col >> 1, aa = col & 1;
            float s0 = conv ? pc4[0] : pd4[0];
            float s1 = conv ? pc4[1] : pd4[1];
#pragma unroll
            for (int m = 0; m < 8; ++m) {
                float th = (float)m * 0.7853981633974483f;
                float csv = cosf(th), snv = sinf(th);
                float bas = (aa == 0) ? (s0*csv - s1*snv) : (s0*snv + s1*csv);
                float wv;
                if (conv) wv = Wc[(((co*C + cc)*8 + ((nn - m)&7))*3 + rr)*16 + ((tt - 2*m)&15)];
                else      wv = Wd[(co*C + cc)*8 + ((m - nn)&7)];
                val += wv * bas;
            }
        }
    }
    Bm[e] = val;
}

// ---------------------------------------------------------------- split-K register-tiled f32 GEMM
template<int N>
__global__ __launch_bounds__(256) void gemm_tile(const float* __restrict__ A, int Kdim,
                                                 const float* __restrict__ B,
                                                 float* __restrict__ Cpart)
{
    constexpr int CT = N/16;               // 1, 4, 8
    __shared__ float As[32][68];           // k-major [kk][row], padded
    __shared__ float Bs[32][N];
    int tid = threadIdx.x;
    int tr = tid & 15, tc = tid >> 4;
    int m0 = blockIdx.x * 64;
    int k0base = blockIdx.y * 224;
    float acc[4][CT];
#pragma unroll
    for (int i = 0; i < 4; ++i)
#pragma unroll
        for (int u = 0; u < CT; ++u) acc[i][u] = 0.0f;

    int ar = tid >> 2, aq = (tid & 3) * 8;
    for (int k0 = 0; k0 < 224; k0 += 32) {
        const float* Ap = A + (size_t)(m0 + ar)*Kdim + k0base + k0 + aq;
        float4 av0 = *(const float4*)(Ap);
        float4 av1 = *(const float4*)(Ap + 4);
        As[aq+0][ar] = av0.x; As[aq+1][ar] = av0.y; As[aq+2][ar] = av0.z; As[aq+3][ar] = av0.w;
        As[aq+4][ar] = av1.x; As[aq+5][ar] = av1.y; As[aq+6][ar] = av1.z; As[aq+7][ar] = av1.w;
#pragma unroll
        for (int u = 0; u < (8*N + 255)/256; ++u) {
            int idx = tid + 256*u;
            if (idx < 8*N) {
                int row = idx / (N/4), c4 = idx % (N/4);
                *(float4*)&Bs[row][c4*4] = *(const float4*)(B + (size_t)(k0base + k0 + row)*N + c4*4);
            }
        }
        __syncthreads();
#pragma unroll
        for (int kk = 0; kk < 32; ++kk) {
            float4 a4 = *(const float4*)&As[kk][tr*4];
            if (CT == 1) {
                float bv = Bs[kk][tc];
                acc[0][0] += a4.x*bv; acc[1][0] += a4.y*bv;
                acc[2][0] += a4.z*bv; acc[3][0] += a4.w*bv;
            } else {
#pragma unroll
                for (int uu = 0; uu < CT; uu += 4) {
                    float4 b4 = *(const float4*)&Bs[kk][tc*CT + uu];
                    acc[0][uu+0] += a4.x*b4.x; acc[0][uu+1] += a4.x*b4.y; acc[0][uu+2] += a4.x*b4.z; acc[0][uu+3] += a4.x*b4.w;
                    acc[1][uu+0] += a4.y*b4.x; acc[1][uu+1] += a4.y*b4.y; acc[1][uu+2] += a4.y*b4.z; acc[1][uu+3] += a4.y*b4.w;
                    acc[2][uu+0] += a4.z*b4.x; acc[2][uu+1] += a4.z*b4.y; acc[2][uu+2] += a4.z*b4.z; acc[2][uu+3] += a4.z*b4.w;
                    acc[3][uu+0] += a4.w*b4.x; acc[3][uu+1] += a4.w*b4.y; acc[3][uu+2] += a4.w*b4.z; acc[3][uu+3] += a4.w*b4.w;
                }
            }
        }
        __syncthreads();
    }
    float* Cp = Cpart + ((size_t)blockIdx.y*1024 + m0)*N;
#pragma unroll
    for (int i = 0; i < 4; ++i)
#pragma unroll
        for (int u = 0; u < CT; ++u)
            Cp[(size_t)(tr*4 + i)*N + tc*CT + u] = acc[i][u];
}

// ---------------------------------------------------------------- epilogue: split-reduce + residual + mag_act
__global__ void epilogue_kernel(const float* __restrict__ Cpart, int S, int O, int res,
                                float* __restrict__ outBuf, float* __restrict__ actDst, int actStride)
{
    int id = blockIdx.x*blockDim.x + threadIdx.x;
    if (id >= NPART*O) return;
    int p = id / O, c = id % O;
    int O8 = O*8;
    float x[8];
#pragma unroll
    for (int m = 0; m < 8; ++m) x[m] = 0.0f;
    for (int s = 0; s < S; ++s) {
        const float4* q = (const float4*)(Cpart + ((size_t)(s*1024 + p))*O8 + c*8);
        float4 u0 = q[0], u1 = q[1];
        x[0]+=u0.x; x[1]+=u0.y; x[2]+=u0.z; x[3]+=u0.w;
        x[4]+=u1.x; x[5]+=u1.y; x[6]+=u1.z; x[7]+=u1.w;
    }
    float* ob = outBuf + (size_t)p*O8 + c*8;
    float mag = 1e-6f;
#pragma unroll
    for (int m = 0; m < 8; ++m) {
        float v = x[m];
        if (res) v += ob[m];
        x[m] = v; mag += v*v;
    }
#pragma unroll
    for (int m = 0; m < 8; ++m) ob[m] = x[m];
    float sc = fmaxf(mag - 0.2f, 0.0f) / mag;
    float* ad = actDst + (size_t)p*actStride + c*8;
#pragma unroll
    for (int m = 0; m < 8; ++m) ad[m] = x[m]*sc;
}

// ---------------------------------------------------------------- final outputs (S splits, N=16 partials)
__global__ void final_kernel(const float* __restrict__ Cpart, int S, const float* __restrict__ p1,
                             const float* __restrict__ p0, float* __restrict__ out)
{
    int p = blockIdx.x*blockDim.x + threadIdx.x;
    if (p >= NPART) return;
    float c[6];
#pragma unroll
    for (int t = 0; t < 6; ++t) c[t] = 0.0f;
    for (int s = 0; s < S; ++s) {
        const float* q = Cpart + ((size_t)(s*1024 + p))*16;
#pragma unroll
        for (int t = 0; t < 6; ++t) c[t] += q[t];
    }
    const float sc = 0.0078125f;  // 1/128
#pragma unroll
    for (int t = 0; t < 6; ++t) c[t] *= sc;
    float pcx = p1[p*2+0] + c[0], pcy = p1[p*2+1] + c[1];
    out[p*2+0] = pcx; out[p*2+1] = pcy;
    out[2048 + p*2+0] = pcx - p0[p*2+0];
    out[2048 + p*2+1] = pcy - p0[p*2+1];
    out[4096 + p*4+0] = c[2]; out[4096 + p*4+1] = c[3];
    out[4096 + p*4+2] = c[4]; out[4096 + p*4+3] = c[5];
}

// ---------------------------------------------------------------- launch
extern "C" void kernel_launch(void* const* d_in, const int* in_sizes, int n_in,
                              void* d_out, int out_size, void* d_ws, size_t ws_size,
                              hipStream_t stream)
{
    const float* p0_enc  = (const float*)d_in[0];
    const float* v0_enc  = (const float*)d_in[1];
    const float* p0      = (const float*)d_in[2];
    const float* v0      = (const float*)d_in[3];
    const float* a       = (const float*)d_in[4];
    const float* mask    = (const float*)d_in[5];
    const float* lift_c0 = (const float*)d_in[6];
    const float* Wc0     = (const float*)d_in[7];
    const float* lift_d0 = (const float*)d_in[8];
    const float* Wd0     = (const float*)d_in[9];
    const float* Wc1     = (const float*)d_in[10];
    const float* Wd1     = (const float*)d_in[11];
    const float* Wc2     = (const float*)d_in[12];
    const float* Wd2     = (const float*)d_in[13];
    const float* Wc3     = (const float*)d_in[14];
    const float* Wd3     = (const float*)d_in[15];
    const float* Wc4     = (const float*)d_in[16];
    const float* pc4     = (const float*)d_in[17];
    const float* Wd4     = (const float*)d_in[18];
    const float* pd4     = (const float*)d_in[19];
    float* out = (float*)d_out;

    float* wsf    = (float*)d_ws;
    float* featsC = wsf;                               // 131072
    float* p1     = featsC + 131072;                   // 2048
    float* Ew     = p1 + 2048;                         // 1024*2048 = 2097152
    unsigned short* Ej = (unsigned short*)(Ew + 2097152);  // 2097152 ushort = 1048576 floats
    int*   offG   = (int*)(Ew + 2097152 + 1048576);    // 1024*64 = 65536
    float* Fbuf   = (float*)offG + 65536;              // 6422528
    float* Cpart  = Fbuf + 1024*6272;                  // 1835008 (28*1024*64 = 14*1024*128)
    float* outBuf = Cpart + 1835008;                   // 131072
    float* Bm0    = outBuf + 131072;                   // 6272*64
    float* Bm1    = Bm0 + 6272*64;                     // 3136*64
    float* Bm2    = Bm1 + 3136*64;                     // 3136*128
    float* Bm3    = Bm2 + 3136*128;                    // 6272*64
    float* Bm4    = Bm3 + 6272*64;                     // 3136*16

    prep_kernel<<<NPART, 128, 0, stream>>>(p0_enc, v0_enc, p0, v0, a, lift_c0, lift_d0,
                                           featsC, Fbuf, p1);
    pairs_kernel<<<NPART, 256, 0, stream>>>(p1, mask, Ew, Ej, offG);

    {   // expand B matrices
        int t0 = 6272*64;  expand_kernel<<<(t0+255)/256, 256, 0, stream>>>(Wc0, Wd0, pc4, pd4, Bm0, 16,  64, t0, 1);
        int t1 = 3136*64;  expand_kernel<<<(t1+255)/256, 256, 0, stream>>>(Wc1, Wd1, pc4, pd4, Bm1,  8,  64, t1, 0);
        int t2 = 3136*128; expand_kernel<<<(t2+255)/256, 256, 0, stream>>>(Wc2, Wd2, pc4, pd4, Bm2,  8, 128, t2, 0);
        int t3 = 6272*64;  expand_kernel<<<(t3+255)/256, 256, 0, stream>>>(Wc3, Wd3, pc4, pd4, Bm3, 16,  64, t3, 0);
        int t4 = 3136*16;  expand_kernel<<<(t4+255)/256, 256, 0, stream>>>(Wc4, Wd4, pc4, pd4, Bm4,  8,  16, t4, 2);
    }

    // Layer 0  (C8=128, K=6272, S=28): both channel-halves in one dispatch (blockIdx.y)
    aggregate_kernel<8><<<dim3(128,2), 512, 0, stream>>>(featsC, 128, 128, Ew, Ej, offG, Fbuf, 6272);
    gemm_tile<64><<<dim3(16,28), 256, 0, stream>>>(Fbuf, 6272, Bm0, Cpart);
    epilogue_kernel<<<(NPART*8+63)/64, 64, 0, stream>>>(Cpart, 28, 8, 0, outBuf, Fbuf + 3072, 3136);
    // Layer 1  (C8=64, K=3136, S=14, residual)
    aggregate_kernel<4><<<dim3(256,1), 512, 0, stream>>>(Fbuf + 3072, 3136, 64, Ew, Ej, offG, Fbuf, 3136);
    gemm_tile<64><<<dim3(16,14), 256, 0, stream>>>(Fbuf, 3136, Bm1, Cpart);
    epilogue_kernel<<<(NPART*8+63)/64, 64, 0, stream>>>(Cpart, 14, 8, 1, outBuf, Fbuf + 3072, 3136);
    // Layer 2  (C8=64 -> O=16, S=14)
    aggregate_kernel<4><<<dim3(256,1), 512, 0, stream>>>(Fbuf + 3072, 3136, 64, Ew, Ej, offG, Fbuf, 3136);
    gemm_tile<128><<<dim3(16,14), 256, 0, stream>>>(Fbuf, 3136, Bm2, Cpart);
    epilogue_kernel<<<(NPART*16+63)/64, 64, 0, stream>>>(Cpart, 14, 16, 0, outBuf, Fbuf + 6144, 6272);
    // Layer 3  (C8=128 -> O=8, S=28)
    aggregate_kernel<8><<<dim3(128,2), 512, 0, stream>>>(Fbuf + 6144, 6272, 128, Ew, Ej, offG, Fbuf, 6272);
    gemm_tile<64><<<dim3(16,28), 256, 0, stream>>>(Fbuf, 6272, Bm3, Cpart);
    epilogue_kernel<<<(NPART*8+63)/64, 64, 0, stream>>>(Cpart, 28, 8, 0, outBuf, Fbuf + 3072, 3136);
    // Layer 4  (C8=64 -> N=16 padded, proj folded, S=14)
    aggregate_kernel<4><<<dim3(256,1), 512, 0, stream>>>(Fbuf + 3072, 3136, 64, Ew, Ej, offG, Fbuf, 3136);
    gemm_tile<16><<<dim3(16,14), 256, 0, stream>>>(Fbuf, 3136, Bm4, Cpart);
    final_kernel<<<4, 256, 0, stream>>>(Cpart, 14, p1, p0, out);
}